// Round 2
// baseline (1249.017 us; speedup 1.0000x reference)
//
#include <hip/hip_runtime.h>

typedef short short8 __attribute__((ext_vector_type(8)));
typedef float floatx4 __attribute__((ext_vector_type(4)));
typedef unsigned short u16;

__device__ __forceinline__ float bits2f(u16 u) {
  union { unsigned int i; float f; } w;
  w.i = ((unsigned int)u) << 16;
  return w.f;
}

__device__ __forceinline__ u16 f2bf(float f) {
  union { float f; unsigned int i; } w;
  w.f = f;
  unsigned int x = w.i;
  unsigned int r = (x + 0x7FFFu + ((x >> 16) & 1u)) >> 16;  // RNE
  return (u16)r;
}

// ------------- transpose+convert: WT_bf16[n][k] = W_f32[k][n] ----------------
__global__ __launch_bounds__(256) void transpose_k(const float* __restrict__ W,
                                                   u16* __restrict__ WT,
                                                   int K, int N) {
  __shared__ float tile[32][33];
  int tx = threadIdx.x & 31;
  int ty = threadIdx.x >> 5;  // 0..7
  int n0 = blockIdx.x * 32;
  int k0 = blockIdx.y * 32;
#pragma unroll
  for (int i = 0; i < 4; i++)
    tile[ty + i * 8][tx] = W[(size_t)(k0 + ty + i * 8) * N + n0 + tx];
  __syncthreads();
#pragma unroll
  for (int i = 0; i < 4; i++)
    WT[(size_t)(n0 + ty + i * 8) * K + k0 + tx] = f2bf(tile[tx][ty + i * 8]);
}

// ------------- GEMM: C[M,N] = A[M,K] @ BT[N,K]^T + bias, optional GELU -------
// A is fp32 (a_fp32=1) or bf16; BT is bf16; C is fp32 (c_fp32=1) or bf16.
__global__ __launch_bounds__(256) void gemm_kernel(
    const void* __restrict__ Av, const u16* __restrict__ BT,
    const float* __restrict__ bias, void* __restrict__ Cv,
    int M, int N, int K, int act, int a_fp32, int c_fp32) {
  __shared__ __align__(16) u16 As[64][40];
  __shared__ __align__(16) u16 Bs[64][40];
  int tid = threadIdx.x;
  int m0 = blockIdx.y * 64;
  int n0 = blockIdx.x * 64;
  int wave = tid >> 6;
  int lane = tid & 63;
  int wm = (wave & 1) * 32;
  int wn = (wave >> 1) * 32;
  int l15 = lane & 15;
  int quad = lane >> 4;

  floatx4 acc[2][2];
  floatx4 zero = {0.f, 0.f, 0.f, 0.f};
#pragma unroll
  for (int mi = 0; mi < 2; mi++)
#pragma unroll
    for (int ni = 0; ni < 2; ni++) acc[mi][ni] = zero;

  int srow = tid >> 2;        // 0..63
  int scol = (tid & 3) * 8;   // 0,8,16,24
  const u16* Ab = (const u16*)Av + (size_t)(m0 + srow) * K + scol;
  const float* Af = (const float*)Av + (size_t)(m0 + srow) * K + scol;
  const u16* Bg = BT + (size_t)(n0 + srow) * K + scol;

  for (int k0 = 0; k0 < K; k0 += 32) {
    if (a_fp32) {
      float4 a0 = *(const float4*)(Af + k0);
      float4 a1 = *(const float4*)(Af + k0 + 4);
      u16 tmp[8];
      tmp[0] = f2bf(a0.x); tmp[1] = f2bf(a0.y); tmp[2] = f2bf(a0.z); tmp[3] = f2bf(a0.w);
      tmp[4] = f2bf(a1.x); tmp[5] = f2bf(a1.y); tmp[6] = f2bf(a1.z); tmp[7] = f2bf(a1.w);
      *(int4*)(&As[srow][scol]) = *(const int4*)tmp;
    } else {
      *(int4*)(&As[srow][scol]) = *(const int4*)(Ab + k0);
    }
    *(int4*)(&Bs[srow][scol]) = *(const int4*)(Bg + k0);
    __syncthreads();
    short8 afrag[2], bfrag[2];
#pragma unroll
    for (int mi = 0; mi < 2; mi++)
      afrag[mi] = *(const short8*)(&As[wm + mi * 16 + l15][quad * 8]);
#pragma unroll
    for (int ni = 0; ni < 2; ni++)
      bfrag[ni] = *(const short8*)(&Bs[wn + ni * 16 + l15][quad * 8]);
#pragma unroll
    for (int mi = 0; mi < 2; mi++)
#pragma unroll
      for (int ni = 0; ni < 2; ni++)
        acc[mi][ni] = __builtin_amdgcn_mfma_f32_16x16x32_bf16(
            afrag[mi], bfrag[ni], acc[mi][ni], 0, 0, 0);
    __syncthreads();
  }

#pragma unroll
  for (int mi = 0; mi < 2; mi++) {
#pragma unroll
    for (int ni = 0; ni < 2; ni++) {
      int col = n0 + wn + ni * 16 + l15;
      float bv = bias[col];
#pragma unroll
      for (int r = 0; r < 4; r++) {
        int row = m0 + wm + mi * 16 + quad * 4 + r;
        float v = acc[mi][ni][r] + bv;
        if (act == 1) v = 0.5f * v * (1.0f + erff(v * 0.70710678118654752f));
        if (c_fp32) ((float*)Cv)[(size_t)row * N + col] = v;
        else        ((u16*)Cv)[(size_t)row * N + col] = f2bf(v);
      }
    }
  }
}

// ------------- fused attention: block per (b,h, 16-query tile) ---------------
__global__ __launch_bounds__(256) void attn_kernel(
    const u16* __restrict__ qg, const u16* __restrict__ kg,
    const u16* __restrict__ vg, u16* __restrict__ ctxg) {
  __shared__ float Qs[16][65];
  __shared__ float KVs[64][65];
  __shared__ float Ss[16][516];  // pad 512->516: distinct banks across row groups
  int bh = blockIdx.x;           // 0..191
  int b = bh / 12;
  int h = bh - b * 12;
  int tid = threadIdx.x;
  size_t base = ((size_t)b * 512) * 768 + (size_t)h * 64;
  int q0 = blockIdx.y * 16;

  {  // load Q tile, scaled by 1/sqrt(64)
    int i = tid >> 4;
    int d0 = (tid & 15) * 4;
    int2 raw = *(const int2*)(qg + base + (size_t)(q0 + i) * 768 + d0);
    const u16* s = (const u16*)&raw;
#pragma unroll
    for (int j = 0; j < 4; j++) Qs[i][d0 + j] = bits2f(s[j]) * 0.125f;
  }
  __syncthreads();

  // scores S = (Q/8) K^T, K in 8 chunks of 64 rows
  for (int c = 0; c < 8; c++) {
    {
      int r = tid >> 2;            // 0..63
      int dd = (tid & 3) * 16;     // 0,16,32,48
      const u16* kp = kg + base + (size_t)(c * 64 + r) * 768 + dd;
#pragma unroll
      for (int t4 = 0; t4 < 2; t4++) {
        int4 raw = *(const int4*)(kp + t4 * 8);
        const u16* s = (const u16*)&raw;
#pragma unroll
        for (int j = 0; j < 8; j++) KVs[r][dd + t4 * 8 + j] = bits2f(s[j]);
      }
    }
    __syncthreads();
    for (int idx = tid; idx < 16 * 64; idx += 256) {
      int i = idx >> 6;
      int kk = idx & 63;
      float s = 0.f;
#pragma unroll 8
      for (int d = 0; d < 64; d++) s += Qs[i][d] * KVs[kk][d];
      Ss[i][c * 64 + kk] = s;
    }
    __syncthreads();
  }

  {  // softmax: 16 lanes per row
    int i = tid >> 4;
    int l = tid & 15;
    float mx = -1e30f;
    for (int kk = l; kk < 512; kk += 16) mx = fmaxf(mx, Ss[i][kk]);
#pragma unroll
    for (int off = 8; off > 0; off >>= 1) mx = fmaxf(mx, __shfl_xor(mx, off, 16));
    float sum = 0.f;
    for (int kk = l; kk < 512; kk += 16) {
      float p = __expf(Ss[i][kk] - mx);
      Ss[i][kk] = p;
      sum += p;
    }
#pragma unroll
    for (int off = 8; off > 0; off >>= 1) sum += __shfl_xor(sum, off, 16);
    float inv = 1.0f / sum;
    for (int kk = l; kk < 512; kk += 16) Ss[i][kk] *= inv;
  }
  __syncthreads();

  // ctx = P V, V in 8 chunks of 64 rows
  float acc0 = 0.f, acc1 = 0.f, acc2 = 0.f, acc3 = 0.f;
  int i = tid >> 4;
  int d0 = (tid & 15) * 4;
  for (int c = 0; c < 8; c++) {
    {
      int r = tid >> 2;
      int dd = (tid & 3) * 16;
      const u16* vp = vg + base + (size_t)(c * 64 + r) * 768 + dd;
#pragma unroll
      for (int t4 = 0; t4 < 2; t4++) {
        int4 raw = *(const int4*)(vp + t4 * 8);
        const u16* s = (const u16*)&raw;
#pragma unroll
        for (int j = 0; j < 8; j++) KVs[r][dd + t4 * 8 + j] = bits2f(s[j]);
      }
    }
    __syncthreads();
    for (int kk = 0; kk < 64; kk++) {
      float p = Ss[i][c * 64 + kk];
      acc0 += p * KVs[kk][d0 + 0];
      acc1 += p * KVs[kk][d0 + 1];
      acc2 += p * KVs[kk][d0 + 2];
      acc3 += p * KVs[kk][d0 + 3];
    }
    __syncthreads();
  }
  u16* cp = ctxg + base + (size_t)(q0 + i) * 768 + d0;
  cp[0] = f2bf(acc0);
  cp[1] = f2bf(acc1);
  cp[2] = f2bf(acc2);
  cp[3] = f2bf(acc3);
}

// ------------- LN1: out_bf16 = LN(a_bf16 + r_f32) ----------------------------
__global__ __launch_bounds__(256) void ln1_kernel(
    const u16* __restrict__ a, const float* __restrict__ r,
    const float* __restrict__ g, const float* __restrict__ bb,
    u16* __restrict__ out) {
  int row = blockIdx.x;
  int tid = threadIdx.x;
  __shared__ float red[4];
  const u16* ap = a + (size_t)row * 768;
  const float* rp = r + (size_t)row * 768;
  float x0 = bits2f(ap[tid]) + rp[tid];
  float x1 = bits2f(ap[tid + 256]) + rp[tid + 256];
  float x2 = bits2f(ap[tid + 512]) + rp[tid + 512];
  float s = x0 + x1 + x2;
#pragma unroll
  for (int off = 32; off > 0; off >>= 1) s += __shfl_xor(s, off, 64);
  if ((tid & 63) == 0) red[tid >> 6] = s;
  __syncthreads();
  float mu = (red[0] + red[1] + red[2] + red[3]) * (1.0f / 768.0f);
  float d0 = x0 - mu, d1 = x1 - mu, d2 = x2 - mu;
  float vs = d0 * d0 + d1 * d1 + d2 * d2;
#pragma unroll
  for (int off = 32; off > 0; off >>= 1) vs += __shfl_xor(vs, off, 64);
  __syncthreads();
  if ((tid & 63) == 0) red[tid >> 6] = vs;
  __syncthreads();
  float var = (red[0] + red[1] + red[2] + red[3]) * (1.0f / 768.0f);
  float rstd = rsqrtf(var + 1e-12f);
  size_t o = (size_t)row * 768;
  out[o + tid]       = f2bf(d0 * rstd * g[tid] + bb[tid]);
  out[o + tid + 256] = f2bf(d1 * rstd * g[tid + 256] + bb[tid + 256]);
  out[o + tid + 512] = f2bf(d2 * rstd * g[tid + 512] + bb[tid + 512]);
}

// ------------- LN2: out_f32 = LN(a_f32 + r_bf16), in-place safe --------------
__global__ __launch_bounds__(256) void ln2_kernel(
    const float* __restrict__ a, const u16* __restrict__ r,
    const float* __restrict__ g, const float* __restrict__ bb,
    float* __restrict__ out) {
  int row = blockIdx.x;
  int tid = threadIdx.x;
  __shared__ float red[4];
  const float* ap = a + (size_t)row * 768;
  const u16* rp = r + (size_t)row * 768;
  float x0 = ap[tid] + bits2f(rp[tid]);
  float x1 = ap[tid + 256] + bits2f(rp[tid + 256]);
  float x2 = ap[tid + 512] + bits2f(rp[tid + 512]);
  float s = x0 + x1 + x2;
#pragma unroll
  for (int off = 32; off > 0; off >>= 1) s += __shfl_xor(s, off, 64);
  if ((tid & 63) == 0) red[tid >> 6] = s;
  __syncthreads();
  float mu = (red[0] + red[1] + red[2] + red[3]) * (1.0f / 768.0f);
  float d0 = x0 - mu, d1 = x1 - mu, d2 = x2 - mu;
  float vs = d0 * d0 + d1 * d1 + d2 * d2;
#pragma unroll
  for (int off = 32; off > 0; off >>= 1) vs += __shfl_xor(vs, off, 64);
  __syncthreads();
  if ((tid & 63) == 0) red[tid >> 6] = vs;
  __syncthreads();
  float var = (red[0] + red[1] + red[2] + red[3]) * (1.0f / 768.0f);
  float rstd = rsqrtf(var + 1e-12f);
  size_t o = (size_t)row * 768;
  out[o + tid]       = d0 * rstd * g[tid] + bb[tid];
  out[o + tid + 256] = d1 * rstd * g[tid + 256] + bb[tid + 256];
  out[o + tid + 512] = d2 * rstd * g[tid + 512] + bb[tid + 512];
}

extern "C" void kernel_launch(void* const* d_in, const int* in_sizes, int n_in,
                              void* d_out, int out_size, void* d_ws, size_t ws_size,
                              hipStream_t stream) {
  (void)in_sizes; (void)n_in; (void)out_size; (void)ws_size;
  const float* x    = (const float*)d_in[0];
  const float* Wq   = (const float*)d_in[1];
  const float* bq   = (const float*)d_in[2];
  const float* Wk   = (const float*)d_in[3];
  const float* bk   = (const float*)d_in[4];
  const float* Wv   = (const float*)d_in[5];
  const float* bv   = (const float*)d_in[6];
  const float* Wo   = (const float*)d_in[7];
  const float* bo   = (const float*)d_in[8];
  const float* ln1g = (const float*)d_in[9];
  const float* ln1b = (const float*)d_in[10];
  const float* W1   = (const float*)d_in[11];
  const float* b1   = (const float*)d_in[12];
  const float* W2   = (const float*)d_in[13];
  const float* b2   = (const float*)d_in[14];
  const float* ln2g = (const float*)d_in[15];
  const float* ln2b = (const float*)d_in[16];

  const int M = 16 * 512, H = 768, FF = 3072;
  const size_t MH = (size_t)M * H;
  const size_t HH = (size_t)H * H;

  // ws layout (u16 elements):
  // [0,4MH): q,k,v,ctx  -> later ffn1 [M,FF] (exactly 4MH); aob aliases q
  // [4MH,5MH): hb
  // [5MH, 5MH+4HH): WTq,WTk,WTv,WTo -> later WT2 [H*FF == 4HH]
  // [5MH+4HH, +FF*H): WT1
  u16* ws   = (u16*)d_ws;
  u16* qb   = ws;
  u16* kb   = ws + MH;
  u16* vb   = ws + 2 * MH;
  u16* ctxb = ws + 3 * MH;
  u16* ffn1 = ws;       // aliases q..ctx (dead by then)
  u16* aob  = qb;       // aliases q (dead after attention)
  u16* hb   = ws + 4 * MH;
  u16* WTq  = ws + 5 * MH;
  u16* WTk  = WTq + HH;
  u16* WTv  = WTk + HH;
  u16* WTo  = WTv + HH;
  u16* WT2  = WTq;      // H*FF == 4*HH, reuses WTq..WTo after attn-out GEMM
  u16* WT1  = WTq + 4 * HH;  // FF*H
  float* outf = (float*)d_out;

  dim3 tb(256);
  transpose_k<<<dim3(H / 32, H / 32), tb, 0, stream>>>(Wq, WTq, H, H);
  transpose_k<<<dim3(H / 32, H / 32), tb, 0, stream>>>(Wk, WTk, H, H);
  transpose_k<<<dim3(H / 32, H / 32), tb, 0, stream>>>(Wv, WTv, H, H);
  transpose_k<<<dim3(H / 32, H / 32), tb, 0, stream>>>(Wo, WTo, H, H);

  gemm_kernel<<<dim3(H / 64, M / 64), tb, 0, stream>>>(x, WTq, bq, qb, M, H, H, 0, 1, 0);
  gemm_kernel<<<dim3(H / 64, M / 64), tb, 0, stream>>>(x, WTk, bk, kb, M, H, H, 0, 1, 0);
  gemm_kernel<<<dim3(H / 64, M / 64), tb, 0, stream>>>(x, WTv, bv, vb, M, H, H, 0, 1, 0);

  attn_kernel<<<dim3(192, 32), tb, 0, stream>>>(qb, kb, vb, ctxb);

  gemm_kernel<<<dim3(H / 64, M / 64), tb, 0, stream>>>(ctxb, WTo, bo, aob, M, H, H, 0, 0, 0);
  ln1_kernel<<<dim3(M), tb, 0, stream>>>(aob, x, ln1g, ln1b, hb);

  transpose_k<<<dim3(FF / 32, H / 32), tb, 0, stream>>>(W1, WT1, H, FF);
  transpose_k<<<dim3(H / 32, FF / 32), tb, 0, stream>>>(W2, WT2, FF, H);

  gemm_kernel<<<dim3(FF / 64, M / 64), tb, 0, stream>>>(hb, WT1, b1, ffn1, M, FF, H, 1, 0, 0);
  gemm_kernel<<<dim3(H / 64, M / 64), tb, 0, stream>>>(ffn1, WT2, b2, outf, M, H, FF, 0, 0, 1);
  ln2_kernel<<<dim3(M), tb, 0, stream>>>(outf, hb, ln2g, ln2b, outf);
}

// Round 3
// 540.955 us; speedup vs baseline: 2.3089x; 2.3089x over previous
//
#include <hip/hip_runtime.h>

typedef short short8 __attribute__((ext_vector_type(8)));
typedef float floatx4 __attribute__((ext_vector_type(4)));
typedef unsigned short u16;

__device__ __forceinline__ float bits2f(u16 u) {
  union { unsigned int i; float f; } w;
  w.i = ((unsigned int)u) << 16;
  return w.f;
}

__device__ __forceinline__ u16 f2bf(float f) {
  union { float f; unsigned int i; } w;
  w.f = f;
  unsigned int x = w.i;
  unsigned int r = (x + 0x7FFFu + ((x >> 16) & 1u)) >> 16;  // RNE
  return (u16)r;
}

// ------------- transpose+convert: WT_bf16[n][k] = W_f32[k][n] ----------------
__global__ __launch_bounds__(256) void transpose_k(const float* __restrict__ W,
                                                   u16* __restrict__ WT,
                                                   int K, int N) {
  __shared__ float tile[32][33];
  int tx = threadIdx.x & 31;
  int ty = threadIdx.x >> 5;  // 0..7
  int n0 = blockIdx.x * 32;
  int k0 = blockIdx.y * 32;
#pragma unroll
  for (int i = 0; i < 4; i++)
    tile[ty + i * 8][tx] = W[(size_t)(k0 + ty + i * 8) * N + n0 + tx];
  __syncthreads();
#pragma unroll
  for (int i = 0; i < 4; i++)
    WT[(size_t)(n0 + ty + i * 8) * K + k0 + tx] = f2bf(tile[tx][ty + i * 8]);
}

// ------------- GEMM: C[M,N] = A[M,K] @ BT[N,K]^T + bias, optional GELU -------
__global__ __launch_bounds__(256) void gemm_kernel(
    const void* __restrict__ Av, const u16* __restrict__ BT,
    const float* __restrict__ bias, void* __restrict__ Cv,
    int M, int N, int K, int act, int a_fp32, int c_fp32) {
  __shared__ __align__(16) u16 As[64][40];
  __shared__ __align__(16) u16 Bs[64][40];
  int tid = threadIdx.x;
  int m0 = blockIdx.y * 64;
  int n0 = blockIdx.x * 64;
  int wave = tid >> 6;
  int lane = tid & 63;
  int wm = (wave & 1) * 32;
  int wn = (wave >> 1) * 32;
  int l15 = lane & 15;
  int quad = lane >> 4;

  floatx4 acc[2][2];
  floatx4 zero = {0.f, 0.f, 0.f, 0.f};
#pragma unroll
  for (int mi = 0; mi < 2; mi++)
#pragma unroll
    for (int ni = 0; ni < 2; ni++) acc[mi][ni] = zero;

  int srow = tid >> 2;        // 0..63
  int scol = (tid & 3) * 8;   // 0,8,16,24
  const u16* Ab = (const u16*)Av + (size_t)(m0 + srow) * K + scol;
  const float* Af = (const float*)Av + (size_t)(m0 + srow) * K + scol;
  const u16* Bg = BT + (size_t)(n0 + srow) * K + scol;

  for (int k0 = 0; k0 < K; k0 += 32) {
    if (a_fp32) {
      float4 a0 = *(const float4*)(Af + k0);
      float4 a1 = *(const float4*)(Af + k0 + 4);
      u16 tmp[8];
      tmp[0] = f2bf(a0.x); tmp[1] = f2bf(a0.y); tmp[2] = f2bf(a0.z); tmp[3] = f2bf(a0.w);
      tmp[4] = f2bf(a1.x); tmp[5] = f2bf(a1.y); tmp[6] = f2bf(a1.z); tmp[7] = f2bf(a1.w);
      *(int4*)(&As[srow][scol]) = *(const int4*)tmp;
    } else {
      *(int4*)(&As[srow][scol]) = *(const int4*)(Ab + k0);
    }
    *(int4*)(&Bs[srow][scol]) = *(const int4*)(Bg + k0);
    __syncthreads();
    short8 afrag[2], bfrag[2];
#pragma unroll
    for (int mi = 0; mi < 2; mi++)
      afrag[mi] = *(const short8*)(&As[wm + mi * 16 + l15][quad * 8]);
#pragma unroll
    for (int ni = 0; ni < 2; ni++)
      bfrag[ni] = *(const short8*)(&Bs[wn + ni * 16 + l15][quad * 8]);
#pragma unroll
    for (int mi = 0; mi < 2; mi++)
#pragma unroll
      for (int ni = 0; ni < 2; ni++)
        acc[mi][ni] = __builtin_amdgcn_mfma_f32_16x16x32_bf16(
            afrag[mi], bfrag[ni], acc[mi][ni], 0, 0, 0);
    __syncthreads();
  }

#pragma unroll
  for (int mi = 0; mi < 2; mi++) {
#pragma unroll
    for (int ni = 0; ni < 2; ni++) {
      int col = n0 + wn + ni * 16 + l15;
      float bv = bias[col];
#pragma unroll
      for (int r = 0; r < 4; r++) {
        int row = m0 + wm + mi * 16 + quad * 4 + r;
        float v = acc[mi][ni][r] + bv;
        if (act == 1) v = 0.5f * v * (1.0f + erff(v * 0.70710678118654752f));
        if (c_fp32) ((float*)Cv)[(size_t)row * N + col] = v;
        else        ((u16*)Cv)[(size_t)row * N + col] = f2bf(v);
      }
    }
  }
}

// ------------- flash-style MFMA attention: block per (b,h, 64-query tile) ----
// Per wave: 16 q-rows. 8 chunks of 64 keys. S-tile & O in AGPR/VGPR (fp32),
// online softmax in exp2 domain, P round-trips LDS (C-layout -> A-layout).
__global__ __launch_bounds__(256) void attn_kernel(
    const u16* __restrict__ qg, const u16* __restrict__ kg,
    const u16* __restrict__ vg, u16* __restrict__ ctxg) {
  __shared__ __align__(16) u16 Qs[64][72];
  __shared__ __align__(16) u16 Ks[64][72];
  __shared__ __align__(16) u16 Vt[64][72];   // [d][key]
  __shared__ __align__(16) u16 Ps[4][16][72];

  int bh = blockIdx.x;  // 0..191
  int b = bh / 12;
  int h = bh - b * 12;
  int q0 = blockIdx.y * 64;
  size_t base = (size_t)b * 512 * 768 + (size_t)h * 64;
  int tid = threadIdx.x;
  int wave = tid >> 6;
  int lane = tid & 63;
  int l15 = lane & 15;
  int quad = lane >> 4;

  int srow = tid >> 2;         // 0..63
  int sd = (tid & 3) * 16;     // 0,16,32,48

  {  // stage Q tile (bf16, unscaled; scale folded into softmax)
    const u16* qp = qg + base + (size_t)(q0 + srow) * 768 + sd;
    *(int4*)&Qs[srow][sd]     = *(const int4*)qp;
    *(int4*)&Qs[srow][sd + 8] = *(const int4*)(qp + 8);
  }
  __syncthreads();

  short8 aQ[2];
#pragma unroll
  for (int k = 0; k < 2; k++)
    aQ[k] = *(const short8*)&Qs[16 * wave + l15][k * 32 + quad * 8];

  floatx4 O[4];
  float m_r[4], l_r[4];
#pragma unroll
  for (int nt = 0; nt < 4; nt++) O[nt] = (floatx4){0.f, 0.f, 0.f, 0.f};
#pragma unroll
  for (int r = 0; r < 4; r++) { m_r[r] = -1e30f; l_r[r] = 0.f; }

  const float cst = 0.18033688011112042f;  // (1/8) * log2(e)

  for (int c = 0; c < 8; c++) {
    const u16* kp = kg + base + (size_t)(c * 64 + srow) * 768 + sd;
    const u16* vp = vg + base + (size_t)(c * 64 + srow) * 768 + sd;
    int4 kv0 = *(const int4*)kp;
    int4 kv1 = *(const int4*)(kp + 8);
    int4 vv0 = *(const int4*)vp;
    int4 vv1 = *(const int4*)(vp + 8);
    __syncthreads();  // prior chunk's LDS reads done
    *(int4*)&Ks[srow][sd]     = kv0;
    *(int4*)&Ks[srow][sd + 8] = kv1;
    {
      u16 tv[16];
      *(int4*)tv = vv0;
      *(int4*)(tv + 8) = vv1;
#pragma unroll
      for (int j = 0; j < 16; j++) Vt[sd + j][srow] = tv[j];
    }
    __syncthreads();

    // S-tile = Q (16x64) . Kchunk^T (64 keys)
    floatx4 S[4];
#pragma unroll
    for (int nt = 0; nt < 4; nt++) {
      floatx4 s = {0.f, 0.f, 0.f, 0.f};
      short8 bK0 = *(const short8*)&Ks[nt * 16 + l15][quad * 8];
      short8 bK1 = *(const short8*)&Ks[nt * 16 + l15][32 + quad * 8];
      s = __builtin_amdgcn_mfma_f32_16x16x32_bf16(aQ[0], bK0, s, 0, 0, 0);
      s = __builtin_amdgcn_mfma_f32_16x16x32_bf16(aQ[1], bK1, s, 0, 0, 0);
      S[nt] = s;
    }

    // online softmax (exp2 domain); lane holds rows quad*4+r, cols nt*16+l15
#pragma unroll
    for (int r = 0; r < 4; r++) {
      float s0 = S[0][r] * cst, s1 = S[1][r] * cst;
      float s2 = S[2][r] * cst, s3 = S[3][r] * cst;
      S[0][r] = s0; S[1][r] = s1; S[2][r] = s2; S[3][r] = s3;
      float mr = fmaxf(fmaxf(s0, s1), fmaxf(s2, s3));
#pragma unroll
      for (int off = 1; off < 16; off <<= 1) mr = fmaxf(mr, __shfl_xor(mr, off, 16));
      float m_new = fmaxf(m_r[r], mr);
      float alpha = exp2f(m_r[r] - m_new);
      m_r[r] = m_new;
      float p0 = exp2f(s0 - m_new), p1 = exp2f(s1 - m_new);
      float p2 = exp2f(s2 - m_new), p3 = exp2f(s3 - m_new);
      S[0][r] = p0; S[1][r] = p1; S[2][r] = p2; S[3][r] = p3;
      float sum = p0 + p1 + p2 + p3;
#pragma unroll
      for (int off = 1; off < 16; off <<= 1) sum += __shfl_xor(sum, off, 16);
      l_r[r] = l_r[r] * alpha + sum;
      O[0][r] *= alpha; O[1][r] *= alpha; O[2][r] *= alpha; O[3][r] *= alpha;
    }

    // P: C-layout -> LDS -> A-layout (per-wave buffer, same-wave dependency)
#pragma unroll
    for (int nt = 0; nt < 4; nt++)
#pragma unroll
      for (int r = 0; r < 4; r++)
        Ps[wave][quad * 4 + r][nt * 16 + l15] = f2bf(S[nt][r]);

    short8 aP[2];
#pragma unroll
    for (int k = 0; k < 2; k++)
      aP[k] = *(const short8*)&Ps[wave][l15][k * 32 + quad * 8];

    // O += P (16x64) . Vchunk (64x64);  B from Vt[d][key]
#pragma unroll
    for (int nt = 0; nt < 4; nt++) {
      short8 bV0 = *(const short8*)&Vt[nt * 16 + l15][quad * 8];
      short8 bV1 = *(const short8*)&Vt[nt * 16 + l15][32 + quad * 8];
      O[nt] = __builtin_amdgcn_mfma_f32_16x16x32_bf16(aP[0], bV0, O[nt], 0, 0, 0);
      O[nt] = __builtin_amdgcn_mfma_f32_16x16x32_bf16(aP[1], bV1, O[nt], 0, 0, 0);
    }
  }

  // epilogue: ctx = O / l
#pragma unroll
  for (int r = 0; r < 4; r++) {
    float inv = 1.0f / l_r[r];
    int row = q0 + 16 * wave + quad * 4 + r;
    u16* cp = ctxg + base + (size_t)row * 768;
#pragma unroll
    for (int nt = 0; nt < 4; nt++)
      cp[nt * 16 + l15] = f2bf(O[nt][r] * inv);
  }
}

// ------------- LN1: out_bf16 = LN(a_bf16 + r_f32) ----------------------------
__global__ __launch_bounds__(256) void ln1_kernel(
    const u16* __restrict__ a, const float* __restrict__ r,
    const float* __restrict__ g, const float* __restrict__ bb,
    u16* __restrict__ out) {
  int row = blockIdx.x;
  int tid = threadIdx.x;
  __shared__ float red[4];
  const u16* ap = a + (size_t)row * 768;
  const float* rp = r + (size_t)row * 768;
  float x0 = bits2f(ap[tid]) + rp[tid];
  float x1 = bits2f(ap[tid + 256]) + rp[tid + 256];
  float x2 = bits2f(ap[tid + 512]) + rp[tid + 512];
  float s = x0 + x1 + x2;
#pragma unroll
  for (int off = 32; off > 0; off >>= 1) s += __shfl_xor(s, off, 64);
  if ((tid & 63) == 0) red[tid >> 6] = s;
  __syncthreads();
  float mu = (red[0] + red[1] + red[2] + red[3]) * (1.0f / 768.0f);
  float d0 = x0 - mu, d1 = x1 - mu, d2 = x2 - mu;
  float vs = d0 * d0 + d1 * d1 + d2 * d2;
#pragma unroll
  for (int off = 32; off > 0; off >>= 1) vs += __shfl_xor(vs, off, 64);
  __syncthreads();
  if ((tid & 63) == 0) red[tid >> 6] = vs;
  __syncthreads();
  float var = (red[0] + red[1] + red[2] + red[3]) * (1.0f / 768.0f);
  float rstd = rsqrtf(var + 1e-12f);
  size_t o = (size_t)row * 768;
  out[o + tid]       = f2bf(d0 * rstd * g[tid] + bb[tid]);
  out[o + tid + 256] = f2bf(d1 * rstd * g[tid + 256] + bb[tid + 256]);
  out[o + tid + 512] = f2bf(d2 * rstd * g[tid + 512] + bb[tid + 512]);
}

// ------------- LN2: out_f32 = LN(a_f32 + r_bf16), in-place safe --------------
__global__ __launch_bounds__(256) void ln2_kernel(
    const float* __restrict__ a, const u16* __restrict__ r,
    const float* __restrict__ g, const float* __restrict__ bb,
    float* __restrict__ out) {
  int row = blockIdx.x;
  int tid = threadIdx.x;
  __shared__ float red[4];
  const float* ap = a + (size_t)row * 768;
  const u16* rp = r + (size_t)row * 768;
  float x0 = ap[tid] + bits2f(rp[tid]);
  float x1 = ap[tid + 256] + bits2f(rp[tid + 256]);
  float x2 = ap[tid + 512] + bits2f(rp[tid + 512]);
  float s = x0 + x1 + x2;
#pragma unroll
  for (int off = 32; off > 0; off >>= 1) s += __shfl_xor(s, off, 64);
  if ((tid & 63) == 0) red[tid >> 6] = s;
  __syncthreads();
  float mu = (red[0] + red[1] + red[2] + red[3]) * (1.0f / 768.0f);
  float d0 = x0 - mu, d1 = x1 - mu, d2 = x2 - mu;
  float vs = d0 * d0 + d1 * d1 + d2 * d2;
#pragma unroll
  for (int off = 32; off > 0; off >>= 1) vs += __shfl_xor(vs, off, 64);
  __syncthreads();
  if ((tid & 63) == 0) red[tid >> 6] = vs;
  __syncthreads();
  float var = (red[0] + red[1] + red[2] + red[3]) * (1.0f / 768.0f);
  float rstd = rsqrtf(var + 1e-12f);
  size_t o = (size_t)row * 768;
  out[o + tid]       = d0 * rstd * g[tid] + bb[tid];
  out[o + tid + 256] = d1 * rstd * g[tid + 256] + bb[tid + 256];
  out[o + tid + 512] = d2 * rstd * g[tid + 512] + bb[tid + 512];
}

extern "C" void kernel_launch(void* const* d_in, const int* in_sizes, int n_in,
                              void* d_out, int out_size, void* d_ws, size_t ws_size,
                              hipStream_t stream) {
  (void)in_sizes; (void)n_in; (void)out_size; (void)ws_size;
  const float* x    = (const float*)d_in[0];
  const float* Wq   = (const float*)d_in[1];
  const float* bq   = (const float*)d_in[2];
  const float* Wk   = (const float*)d_in[3];
  const float* bk   = (const float*)d_in[4];
  const float* Wv   = (const float*)d_in[5];
  const float* bv   = (const float*)d_in[6];
  const float* Wo   = (const float*)d_in[7];
  const float* bo   = (const float*)d_in[8];
  const float* ln1g = (const float*)d_in[9];
  const float* ln1b = (const float*)d_in[10];
  const float* W1   = (const float*)d_in[11];
  const float* b1   = (const float*)d_in[12];
  const float* W2   = (const float*)d_in[13];
  const float* b2   = (const float*)d_in[14];
  const float* ln2g = (const float*)d_in[15];
  const float* ln2b = (const float*)d_in[16];

  const int M = 16 * 512, H = 768, FF = 3072;
  const size_t MH = (size_t)M * H;
  const size_t HH = (size_t)H * H;

  u16* ws   = (u16*)d_ws;
  u16* qb   = ws;
  u16* kb   = ws + MH;
  u16* vb   = ws + 2 * MH;
  u16* ctxb = ws + 3 * MH;
  u16* ffn1 = ws;       // aliases q..ctx (dead by then)
  u16* aob  = qb;       // aliases q (dead after attention)
  u16* hb   = ws + 4 * MH;
  u16* WTq  = ws + 5 * MH;
  u16* WTk  = WTq + HH;
  u16* WTv  = WTk + HH;
  u16* WTo  = WTv + HH;
  u16* WT2  = WTq;      // H*FF == 4*HH, reuses WTq..WTo after attn-out GEMM
  u16* WT1  = WTq + 4 * HH;  // FF*H
  float* outf = (float*)d_out;

  dim3 tb(256);
  transpose_k<<<dim3(H / 32, H / 32), tb, 0, stream>>>(Wq, WTq, H, H);
  transpose_k<<<dim3(H / 32, H / 32), tb, 0, stream>>>(Wk, WTk, H, H);
  transpose_k<<<dim3(H / 32, H / 32), tb, 0, stream>>>(Wv, WTv, H, H);
  transpose_k<<<dim3(H / 32, H / 32), tb, 0, stream>>>(Wo, WTo, H, H);

  gemm_kernel<<<dim3(H / 64, M / 64), tb, 0, stream>>>(x, WTq, bq, qb, M, H, H, 0, 1, 0);
  gemm_kernel<<<dim3(H / 64, M / 64), tb, 0, stream>>>(x, WTk, bk, kb, M, H, H, 0, 1, 0);
  gemm_kernel<<<dim3(H / 64, M / 64), tb, 0, stream>>>(x, WTv, bv, vb, M, H, H, 0, 1, 0);

  attn_kernel<<<dim3(192, 8), tb, 0, stream>>>(qb, kb, vb, ctxb);

  gemm_kernel<<<dim3(H / 64, M / 64), tb, 0, stream>>>(ctxb, WTo, bo, aob, M, H, H, 0, 0, 0);
  ln1_kernel<<<dim3(M), tb, 0, stream>>>(aob, x, ln1g, ln1b, hb);

  transpose_k<<<dim3(FF / 32, H / 32), tb, 0, stream>>>(W1, WT1, H, FF);
  transpose_k<<<dim3(H / 32, FF / 32), tb, 0, stream>>>(W2, WT2, FF, H);

  gemm_kernel<<<dim3(FF / 64, M / 64), tb, 0, stream>>>(hb, WT1, b1, ffn1, M, FF, H, 1, 0, 0);
  gemm_kernel<<<dim3(H / 64, M / 64), tb, 0, stream>>>(ffn1, WT2, b2, outf, M, H, FF, 0, 0, 1);
  ln2_kernel<<<dim3(M), tb, 0, stream>>>(outf, hb, ln2g, ln2b, outf);
}

// Round 4
// 442.794 us; speedup vs baseline: 2.8208x; 1.2217x over previous
//
#include <hip/hip_runtime.h>

typedef short short8 __attribute__((ext_vector_type(8)));
typedef float floatx4 __attribute__((ext_vector_type(4)));
typedef unsigned short u16;
typedef unsigned int u32;

__device__ __forceinline__ float bits2f(u16 u) {
  union { unsigned int i; float f; } w;
  w.i = ((unsigned int)u) << 16;
  return w.f;
}

__device__ __forceinline__ u16 f2bf(float f) {
  union { float f; unsigned int i; } w;
  w.f = f;
  unsigned int x = w.i;
  unsigned int r = (x + 0x7FFFu + ((x >> 16) & 1u)) >> 16;  // RNE
  return (u16)r;
}

// async global->LDS, 16 B per lane; lds dest = wave-uniform base + lane*16
__device__ __forceinline__ void g2l16(const u16* g, u16* l) {
  __builtin_amdgcn_global_load_lds(
      (const __attribute__((address_space(1))) u32*)(const void*)g,
      (__attribute__((address_space(3))) u32*)(void*)l, 16, 0, 0);
}

// ------------- convert fp32 -> bf16, 8 elems/thread --------------------------
__global__ __launch_bounds__(256) void cvt_bf16_k(const float* __restrict__ x,
                                                  u16* __restrict__ xb, int n8) {
  int i = blockIdx.x * 256 + threadIdx.x;
  if (i >= n8) return;
  const float4* p = (const float4*)x + (size_t)i * 2;
  float4 a = p[0], b = p[1];
  u16 t[8] = {f2bf(a.x), f2bf(a.y), f2bf(a.z), f2bf(a.w),
              f2bf(b.x), f2bf(b.y), f2bf(b.z), f2bf(b.w)};
  *(int4*)(xb + (size_t)i * 8) = *(const int4*)t;
}

// ------------- pack q,k,v biases into one [2304] float -----------------------
__global__ __launch_bounds__(256) void pack_bias_k(const float* __restrict__ bq,
                                                   const float* __restrict__ bk,
                                                   const float* __restrict__ bv,
                                                   float* __restrict__ dst) {
  int i = blockIdx.x * 256 + threadIdx.x;
  if (i < 768) dst[i] = bq[i];
  else if (i < 1536) dst[i] = bk[i - 768];
  else if (i < 2304) dst[i] = bv[i - 1536];
}

// ------------- transpose+convert: WT_bf16[n][k] = W_f32[k][n] ----------------
__global__ __launch_bounds__(256) void transpose_k(const float* __restrict__ W,
                                                   u16* __restrict__ WT,
                                                   int K, int N) {
  __shared__ float tile[32][33];
  int tx = threadIdx.x & 31;
  int ty = threadIdx.x >> 5;
  int n0 = blockIdx.x * 32;
  int k0 = blockIdx.y * 32;
#pragma unroll
  for (int i = 0; i < 4; i++)
    tile[ty + i * 8][tx] = W[(size_t)(k0 + ty + i * 8) * N + n0 + tx];
  __syncthreads();
#pragma unroll
  for (int i = 0; i < 4; i++)
    WT[(size_t)(n0 + ty + i * 8) * K + k0 + tx] = f2bf(tile[tx][ty + i * 8]);
}

// ------------- m97-style GEMM: C[M,N] = A[M,K](lda) @ BT[N,K]^T + bias -------
// BM=128, BK=32, 256 threads. BN=128: 4 waves 2x2, each 64x64 (4x4 mfma tiles).
// BN=64: 4 waves 4x1, each 32x64 (2x4 tiles). global_load_lds width-16 staging.
template <int BN>
__global__ __launch_bounds__(256) void gemm_m97(
    const u16* __restrict__ A, int lda, const u16* __restrict__ BT,
    const float* __restrict__ bias, void* __restrict__ Cv,
    int M, int N, int K, int act, int c_fp32) {
  constexpr int BM = 128, BK = 32;
  __shared__ __align__(16) u16 As[BM * BK];
  __shared__ __align__(16) u16 Bs[BN * BK];
  int tid = threadIdx.x;
  int wave = tid >> 6;
  int lane = tid & 63;
  int l15 = lane & 15;
  int quad = lane >> 4;
  int m0 = blockIdx.y * BM;
  int n0 = blockIdx.x * BN;

  constexpr int MT = (BN == 128) ? 4 : 2;
  constexpr int NT = 4;
  int wm = (BN == 128) ? (wave & 1) * 64 : wave * 32;
  int wn = (BN == 128) ? (wave >> 1) * 64 : 0;

  floatx4 acc[MT][NT];
#pragma unroll
  for (int mi = 0; mi < MT; mi++)
#pragma unroll
    for (int ni = 0; ni < NT; ni++) acc[mi][ni] = (floatx4){0.f, 0.f, 0.f, 0.f};

  // staging: thread t covers LDS bytes [c*4096 + t*16); elem row=c*64+(t>>2),
  // col=(t&3)*8 in the [rows][32] tile. Wave-uniform LDS base + lane*16.
  int srow = tid >> 2;
  int scol = (tid & 3) * 8;
  const u16* Ag0 = A + (size_t)(m0 + srow) * lda + scol;
  const u16* Ag1 = A + (size_t)(m0 + 64 + srow) * lda + scol;
  const u16* Bg0 = BT + (size_t)(n0 + srow) * K + scol;
  u16* AsW0 = As + wave * 512;
  u16* AsW1 = As + 2048 + wave * 512;
  u16* BsW0 = Bs + wave * 512;

  for (int k0 = 0; k0 < K; k0 += BK) {
    g2l16(Ag0 + k0, AsW0);
    g2l16(Ag1 + k0, AsW1);
    g2l16(Bg0 + k0, BsW0);
    if constexpr (BN == 128) {
      const u16* Bg1 = BT + (size_t)(n0 + 64 + srow) * K + scol;
      g2l16(Bg1 + k0, Bs + 2048 + wave * 512);
    }
    __syncthreads();
    short8 af[MT], bfr[NT];
#pragma unroll
    for (int mi = 0; mi < MT; mi++)
      af[mi] = *(const short8*)&As[(wm + mi * 16 + l15) * BK + quad * 8];
#pragma unroll
    for (int ni = 0; ni < NT; ni++)
      bfr[ni] = *(const short8*)&Bs[(wn + ni * 16 + l15) * BK + quad * 8];
#pragma unroll
    for (int mi = 0; mi < MT; mi++)
#pragma unroll
      for (int ni = 0; ni < NT; ni++)
        acc[mi][ni] = __builtin_amdgcn_mfma_f32_16x16x32_bf16(
            af[mi], bfr[ni], acc[mi][ni], 0, 0, 0);
    __syncthreads();
  }

#pragma unroll
  for (int mi = 0; mi < MT; mi++) {
#pragma unroll
    for (int ni = 0; ni < NT; ni++) {
      int col = n0 + wn + ni * 16 + l15;
      float bv = bias[col];
#pragma unroll
      for (int r = 0; r < 4; r++) {
        int row = m0 + wm + mi * 16 + quad * 4 + r;
        float v = acc[mi][ni][r] + bv;
        if (act == 1) v = 0.5f * v * (1.0f + erff(v * 0.70710678118654752f));
        if (c_fp32) ((float*)Cv)[(size_t)row * N + col] = v;
        else        ((u16*)Cv)[(size_t)row * N + col] = f2bf(v);
      }
    }
  }
}

// ------------- flash-style MFMA attention on fused qkv [M,2304] --------------
// q=cols 0..767, k=768..1535, v=1536..2303. ctx written IN-PLACE into q slot.
__global__ __launch_bounds__(256) void attn_kernel(u16* __restrict__ qkv) {
  __shared__ __align__(16) u16 Qs[64][72];
  __shared__ __align__(16) u16 Ks[64][72];
  __shared__ __align__(16) u16 Vt[64][72];   // [d][key]
  __shared__ __align__(16) u16 Ps[4][16][72];

  const int LD = 2304;
  int bh = blockIdx.x;  // 0..191
  int b = bh / 12;
  int h = bh - b * 12;
  int q0 = blockIdx.y * 64;
  size_t base = (size_t)b * 512 * LD + (size_t)h * 64;
  const u16* qg = qkv + base;
  const u16* kg = qkv + base + 768;
  const u16* vg = qkv + base + 1536;
  int tid = threadIdx.x;
  int wave = tid >> 6;
  int lane = tid & 63;
  int l15 = lane & 15;
  int quad = lane >> 4;

  int srow = tid >> 2;
  int sd = (tid & 3) * 16;

  {
    const u16* qp = qg + (size_t)(q0 + srow) * LD + sd;
    *(int4*)&Qs[srow][sd]     = *(const int4*)qp;
    *(int4*)&Qs[srow][sd + 8] = *(const int4*)(qp + 8);
  }
  __syncthreads();

  short8 aQ[2];
#pragma unroll
  for (int k = 0; k < 2; k++)
    aQ[k] = *(const short8*)&Qs[16 * wave + l15][k * 32 + quad * 8];

  floatx4 O[4];
  float m_r[4], l_r[4];
#pragma unroll
  for (int nt = 0; nt < 4; nt++) O[nt] = (floatx4){0.f, 0.f, 0.f, 0.f};
#pragma unroll
  for (int r = 0; r < 4; r++) { m_r[r] = -1e30f; l_r[r] = 0.f; }

  const float cst = 0.18033688011112042f;  // (1/8) * log2(e)

  for (int c = 0; c < 8; c++) {
    const u16* kp = kg + (size_t)(c * 64 + srow) * LD + sd;
    const u16* vp = vg + (size_t)(c * 64 + srow) * LD + sd;
    int4 kv0 = *(const int4*)kp;
    int4 kv1 = *(const int4*)(kp + 8);
    int4 vv0 = *(const int4*)vp;
    int4 vv1 = *(const int4*)(vp + 8);
    __syncthreads();
    *(int4*)&Ks[srow][sd]     = kv0;
    *(int4*)&Ks[srow][sd + 8] = kv1;
    {
      u16 tv[16];
      *(int4*)tv = vv0;
      *(int4*)(tv + 8) = vv1;
#pragma unroll
      for (int j = 0; j < 16; j++) Vt[sd + j][srow] = tv[j];
    }
    __syncthreads();

    floatx4 S[4];
#pragma unroll
    for (int nt = 0; nt < 4; nt++) {
      floatx4 s = {0.f, 0.f, 0.f, 0.f};
      short8 bK0 = *(const short8*)&Ks[nt * 16 + l15][quad * 8];
      short8 bK1 = *(const short8*)&Ks[nt * 16 + l15][32 + quad * 8];
      s = __builtin_amdgcn_mfma_f32_16x16x32_bf16(aQ[0], bK0, s, 0, 0, 0);
      s = __builtin_amdgcn_mfma_f32_16x16x32_bf16(aQ[1], bK1, s, 0, 0, 0);
      S[nt] = s;
    }

#pragma unroll
    for (int r = 0; r < 4; r++) {
      float s0 = S[0][r] * cst, s1 = S[1][r] * cst;
      float s2 = S[2][r] * cst, s3 = S[3][r] * cst;
      float mr = fmaxf(fmaxf(s0, s1), fmaxf(s2, s3));
#pragma unroll
      for (int off = 1; off < 16; off <<= 1) mr = fmaxf(mr, __shfl_xor(mr, off, 16));
      float m_new = fmaxf(m_r[r], mr);
      float alpha = exp2f(m_r[r] - m_new);
      m_r[r] = m_new;
      float p0 = exp2f(s0 - m_new), p1 = exp2f(s1 - m_new);
      float p2 = exp2f(s2 - m_new), p3 = exp2f(s3 - m_new);
      S[0][r] = p0; S[1][r] = p1; S[2][r] = p2; S[3][r] = p3;
      float sum = p0 + p1 + p2 + p3;
#pragma unroll
      for (int off = 1; off < 16; off <<= 1) sum += __shfl_xor(sum, off, 16);
      l_r[r] = l_r[r] * alpha + sum;
      O[0][r] *= alpha; O[1][r] *= alpha; O[2][r] *= alpha; O[3][r] *= alpha;
    }

#pragma unroll
    for (int nt = 0; nt < 4; nt++)
#pragma unroll
      for (int r = 0; r < 4; r++)
        Ps[wave][quad * 4 + r][nt * 16 + l15] = f2bf(S[nt][r]);

    short8 aP[2];
#pragma unroll
    for (int k = 0; k < 2; k++)
      aP[k] = *(const short8*)&Ps[wave][l15][k * 32 + quad * 8];

#pragma unroll
    for (int nt = 0; nt < 4; nt++) {
      short8 bV0 = *(const short8*)&Vt[nt * 16 + l15][quad * 8];
      short8 bV1 = *(const short8*)&Vt[nt * 16 + l15][32 + quad * 8];
      O[nt] = __builtin_amdgcn_mfma_f32_16x16x32_bf16(aP[0], bV0, O[nt], 0, 0, 0);
      O[nt] = __builtin_amdgcn_mfma_f32_16x16x32_bf16(aP[1], bV1, O[nt], 0, 0, 0);
    }
  }

  // epilogue: write ctx back into the q slot (this block owns these rows/cols)
#pragma unroll
  for (int r = 0; r < 4; r++) {
    float inv = 1.0f / l_r[r];
    int row = q0 + 16 * wave + quad * 4 + r;
    u16* cp = qkv + base + (size_t)row * LD;
#pragma unroll
    for (int nt = 0; nt < 4; nt++)
      cp[nt * 16 + l15] = f2bf(O[nt][r] * inv);
  }
}

// ------------- LN1: out_bf16 = LN(a_bf16 + r_f32) ----------------------------
__global__ __launch_bounds__(256) void ln1_kernel(
    const u16* __restrict__ a, const float* __restrict__ r,
    const float* __restrict__ g, const float* __restrict__ bb,
    u16* __restrict__ out) {
  int row = blockIdx.x;
  int tid = threadIdx.x;
  __shared__ float red[4];
  const u16* ap = a + (size_t)row * 768;
  const float* rp = r + (size_t)row * 768;
  float x0 = bits2f(ap[tid]) + rp[tid];
  float x1 = bits2f(ap[tid + 256]) + rp[tid + 256];
  float x2 = bits2f(ap[tid + 512]) + rp[tid + 512];
  float s = x0 + x1 + x2;
#pragma unroll
  for (int off = 32; off > 0; off >>= 1) s += __shfl_xor(s, off, 64);
  if ((tid & 63) == 0) red[tid >> 6] = s;
  __syncthreads();
  float mu = (red[0] + red[1] + red[2] + red[3]) * (1.0f / 768.0f);
  float d0 = x0 - mu, d1 = x1 - mu, d2 = x2 - mu;
  float vs = d0 * d0 + d1 * d1 + d2 * d2;
#pragma unroll
  for (int off = 32; off > 0; off >>= 1) vs += __shfl_xor(vs, off, 64);
  __syncthreads();
  if ((tid & 63) == 0) red[tid >> 6] = vs;
  __syncthreads();
  float var = (red[0] + red[1] + red[2] + red[3]) * (1.0f / 768.0f);
  float rstd = rsqrtf(var + 1e-12f);
  size_t o = (size_t)row * 768;
  out[o + tid]       = f2bf(d0 * rstd * g[tid] + bb[tid]);
  out[o + tid + 256] = f2bf(d1 * rstd * g[tid + 256] + bb[tid + 256]);
  out[o + tid + 512] = f2bf(d2 * rstd * g[tid + 512] + bb[tid + 512]);
}

// ------------- LN2: out_f32 = LN(a_f32 + r_bf16), in-place safe --------------
__global__ __launch_bounds__(256) void ln2_kernel(
    const float* __restrict__ a, const u16* __restrict__ r,
    const float* __restrict__ g, const float* __restrict__ bb,
    float* __restrict__ out) {
  int row = blockIdx.x;
  int tid = threadIdx.x;
  __shared__ float red[4];
  const float* ap = a + (size_t)row * 768;
  const u16* rp = r + (size_t)row * 768;
  float x0 = ap[tid] + bits2f(rp[tid]);
  float x1 = ap[tid + 256] + bits2f(rp[tid + 256]);
  float x2 = ap[tid + 512] + bits2f(rp[tid + 512]);
  float s = x0 + x1 + x2;
#pragma unroll
  for (int off = 32; off > 0; off >>= 1) s += __shfl_xor(s, off, 64);
  if ((tid & 63) == 0) red[tid >> 6] = s;
  __syncthreads();
  float mu = (red[0] + red[1] + red[2] + red[3]) * (1.0f / 768.0f);
  float d0 = x0 - mu, d1 = x1 - mu, d2 = x2 - mu;
  float vs = d0 * d0 + d1 * d1 + d2 * d2;
#pragma unroll
  for (int off = 32; off > 0; off >>= 1) vs += __shfl_xor(vs, off, 64);
  __syncthreads();
  if ((tid & 63) == 0) red[tid >> 6] = vs;
  __syncthreads();
  float var = (red[0] + red[1] + red[2] + red[3]) * (1.0f / 768.0f);
  float rstd = rsqrtf(var + 1e-12f);
  size_t o = (size_t)row * 768;
  out[o + tid]       = d0 * rstd * g[tid] + bb[tid];
  out[o + tid + 256] = d1 * rstd * g[tid + 256] + bb[tid + 256];
  out[o + tid + 512] = d2 * rstd * g[tid + 512] + bb[tid + 512];
}

extern "C" void kernel_launch(void* const* d_in, const int* in_sizes, int n_in,
                              void* d_out, int out_size, void* d_ws, size_t ws_size,
                              hipStream_t stream) {
  (void)in_sizes; (void)n_in; (void)out_size; (void)ws_size;
  const float* x    = (const float*)d_in[0];
  const float* Wq   = (const float*)d_in[1];
  const float* bq   = (const float*)d_in[2];
  const float* Wk   = (const float*)d_in[3];
  const float* bk   = (const float*)d_in[4];
  const float* Wv   = (const float*)d_in[5];
  const float* bv   = (const float*)d_in[6];
  const float* Wo   = (const float*)d_in[7];
  const float* bo   = (const float*)d_in[8];
  const float* ln1g = (const float*)d_in[9];
  const float* ln1b = (const float*)d_in[10];
  const float* W1   = (const float*)d_in[11];
  const float* b1   = (const float*)d_in[12];
  const float* W2   = (const float*)d_in[13];
  const float* b2   = (const float*)d_in[14];
  const float* ln2g = (const float*)d_in[15];
  const float* ln2b = (const float*)d_in[16];

  const int M = 16 * 512, H = 768, FF = 3072;
  const size_t MH = (size_t)M * H;
  const size_t HH = (size_t)H * H;

  // ws (u16 elems): [0,3MH) qkv ; [3MH,4MH) xb -> aob ; ffn1 = [0,4MH)
  // [4MH,5MH) hb ; weights: [5MH,5MH+3HH) WTqkv, +HH WTo, +4HH WT1
  // (WT2 aliases WTqkv..WTo = 4HH) ; biasqkv (2304 floats) after WT1.
  u16* ws    = (u16*)d_ws;
  u16* qkv   = ws;
  u16* xb    = ws + 3 * MH;
  u16* aob   = xb;             // aob overwrites xb (dead after QKV GEMM)
  u16* ffn1  = ws;             // [0,4MH): qkv+aob both dead by FFN1
  u16* hb    = ws + 4 * MH;
  u16* WTqkv = ws + 5 * MH;
  u16* WTo   = WTqkv + 3 * HH;
  u16* WT1   = WTqkv + 4 * HH;
  u16* WT2   = WTqkv;          // 4HH, reused after Wo GEMM
  float* biasqkv = (float*)(WT1 + 4 * HH);
  float* outf = (float*)d_out;

  dim3 tb(256);
  cvt_bf16_k<<<dim3((M * H / 8 + 255) / 256), tb, 0, stream>>>(x, xb, M * H / 8);
  pack_bias_k<<<dim3(9), tb, 0, stream>>>(bq, bk, bv, biasqkv);
  transpose_k<<<dim3(H / 32, H / 32), tb, 0, stream>>>(Wq, WTqkv, H, H);
  transpose_k<<<dim3(H / 32, H / 32), tb, 0, stream>>>(Wk, WTqkv + HH, H, H);
  transpose_k<<<dim3(H / 32, H / 32), tb, 0, stream>>>(Wv, WTqkv + 2 * HH, H, H);
  transpose_k<<<dim3(H / 32, H / 32), tb, 0, stream>>>(Wo, WTo, H, H);
  transpose_k<<<dim3(FF / 32, H / 32), tb, 0, stream>>>(W1, WT1, H, FF);

  // fused QKV: [M,2304] = xb[M,768] @ WTqkv^T
  gemm_m97<128><<<dim3(2304 / 128, M / 128), tb, 0, stream>>>(
      xb, H, WTqkv, biasqkv, qkv, M, 2304, H, 0, 0);

  attn_kernel<<<dim3(192, 8), tb, 0, stream>>>(qkv);

  // attn out: aob[M,768] = ctx(q-slot of qkv, lda=2304) @ WTo^T
  gemm_m97<64><<<dim3(H / 64, M / 128), tb, 0, stream>>>(
      qkv, 2304, WTo, bo, aob, M, H, H, 0, 0);
  ln1_kernel<<<dim3(M), tb, 0, stream>>>(aob, x, ln1g, ln1b, hb);

  transpose_k<<<dim3(H / 32, FF / 32), tb, 0, stream>>>(W2, WT2, FF, H);

  gemm_m97<128><<<dim3(FF / 128, M / 128), tb, 0, stream>>>(
      hb, H, WT1, b1, ffn1, M, FF, H, 1, 0);
  gemm_m97<64><<<dim3(H / 64, M / 128), tb, 0, stream>>>(
      ffn1, FF, WT2, b2, outf, M, H, FF, 0, 1);
  ln2_kernel<<<dim3(M), tb, 0, stream>>>(outf, hb, ln2g, ln2b, outf);
}

// Round 5
// 411.251 us; speedup vs baseline: 3.0371x; 1.0767x over previous
//
#include <hip/hip_runtime.h>

typedef short short8 __attribute__((ext_vector_type(8)));
typedef float floatx4 __attribute__((ext_vector_type(4)));
typedef unsigned short u16;
typedef unsigned int u32;

__device__ __forceinline__ float bits2f(u16 u) {
  union { unsigned int i; float f; } w;
  w.i = ((unsigned int)u) << 16;
  return w.f;
}

__device__ __forceinline__ u16 f2bf(float f) {
  union { float f; unsigned int i; } w;
  w.f = f;
  unsigned int x = w.i;
  unsigned int r = (x + 0x7FFFu + ((x >> 16) & 1u)) >> 16;  // RNE
  return (u16)r;
}

// async global->LDS, 16 B per lane; lds dest = wave-uniform base + lane*16
__device__ __forceinline__ void g2l16(const u16* g, u16* l) {
  __builtin_amdgcn_global_load_lds(
      (const __attribute__((address_space(1))) u32*)(const void*)g,
      (__attribute__((address_space(3))) u32*)(void*)l, 16, 0, 0);
}

// ------------- fused prep: cvt x->bf16, pack qkv bias, 5 weight transposes ---
// blocks: [0,3072) cvt | [3072,3081) bias | [3081,5385) Wq/Wk/Wv/Wo | [5385,7689) W1
__global__ __launch_bounds__(256) void prep_kernel(
    const float* __restrict__ x, u16* __restrict__ xb,
    const float* __restrict__ bq, const float* __restrict__ bk,
    const float* __restrict__ bv, float* __restrict__ biasqkv,
    const float* __restrict__ Wq, const float* __restrict__ Wk,
    const float* __restrict__ Wv, const float* __restrict__ Wo,
    const float* __restrict__ W1,
    u16* __restrict__ WTqkv, u16* __restrict__ WTo, u16* __restrict__ WT1) {
  __shared__ float tile[32][33];
  int bid = blockIdx.x;
  int tid = threadIdx.x;
  if (bid < 3072) {  // cvt: 3072*256*8 == 16*512*768 exactly
    int i = bid * 256 + tid;
    const float4* p = (const float4*)x + (size_t)i * 2;
    float4 a = p[0], b = p[1];
    u16 t[8] = {f2bf(a.x), f2bf(a.y), f2bf(a.z), f2bf(a.w),
                f2bf(b.x), f2bf(b.y), f2bf(b.z), f2bf(b.w)};
    *(int4*)(xb + (size_t)i * 8) = *(const int4*)t;
    return;
  }
  if (bid < 3081) {  // bias pack: 9*256 == 2304 exactly
    int i = (bid - 3072) * 256 + tid;
    biasqkv[i] = (i < 768) ? bq[i] : (i < 1536 ? bk[i - 768] : bv[i - 1536]);
    return;
  }
  const float* W;
  u16* WT;
  int K, N, bx, by;
  if (bid < 5385) {  // 4 square transposes, 576 blocks (24x24) each
    int s = bid - 3081;
    int wsel = s / 576;
    int r = s - wsel * 576;
    K = 768; N = 768; bx = r % 24; by = r / 24;
    if (wsel == 0)      { W = Wq; WT = WTqkv; }
    else if (wsel == 1) { W = Wk; WT = WTqkv + 768 * 768; }
    else if (wsel == 2) { W = Wv; WT = WTqkv + 2 * 768 * 768; }
    else                { W = Wo; WT = WTo; }
  } else {  // W1 [768,3072] -> WT1 [3072,768], 2304 blocks (96x24)
    int r = bid - 5385;
    K = 768; N = 3072; bx = r % 96; by = r / 96;
    W = W1; WT = WT1;
  }
  int tx = tid & 31, ty = tid >> 5;
  int n0 = bx * 32, k0 = by * 32;
#pragma unroll
  for (int i = 0; i < 4; i++)
    tile[ty + i * 8][tx] = W[(size_t)(k0 + ty + i * 8) * N + n0 + tx];
  __syncthreads();
#pragma unroll
  for (int i = 0; i < 4; i++)
    WT[(size_t)(n0 + ty + i * 8) * K + k0 + tx] = f2bf(tile[tx][ty + i * 8]);
}

// ------------- standalone transpose (for W2; WT2 aliases WTqkv) --------------
__global__ __launch_bounds__(256) void transpose_k(const float* __restrict__ W,
                                                   u16* __restrict__ WT,
                                                   int K, int N) {
  __shared__ float tile[32][33];
  int tx = threadIdx.x & 31;
  int ty = threadIdx.x >> 5;
  int n0 = blockIdx.x * 32;
  int k0 = blockIdx.y * 32;
#pragma unroll
  for (int i = 0; i < 4; i++)
    tile[ty + i * 8][tx] = W[(size_t)(k0 + ty + i * 8) * N + n0 + tx];
  __syncthreads();
#pragma unroll
  for (int i = 0; i < 4; i++)
    WT[(size_t)(n0 + ty + i * 8) * K + k0 + tx] = f2bf(tile[tx][ty + i * 8]);
}

// ------------- m97-style GEMM: C[M,N] = A[M,K](lda) @ BT[N,K]^T + bias -------
// BM=128, BK=32, 256 threads. Requires gridDim.y==64 and gridDim.x%6==0 for
// the XCD swizzle: lin%8 -> XCD; each XCD owns 8 m-blocks x all n, iterated in
// 8m x 6n supertiles (A 1.57MB + B 1.18MB < 4MB per-XCD L2).
template <int BN>
__global__ __launch_bounds__(256) void gemm_m97(
    const u16* __restrict__ A, int lda, const u16* __restrict__ BT,
    const float* __restrict__ bias, void* __restrict__ Cv,
    int M, int N, int K, int act, int c_fp32) {
  constexpr int BM = 128, BK = 32;
  __shared__ __align__(16) u16 As[BM * BK];
  __shared__ __align__(16) u16 Bs[BN * BK];
  int tid = threadIdx.x;
  int wave = tid >> 6;
  int lane = tid & 63;
  int l15 = lane & 15;
  int quad = lane >> 4;

  // XCD-aware swizzle
  int nb = gridDim.x;
  int lin = blockIdx.y * nb + blockIdx.x;
  int xcd = lin & 7;
  int i = lin >> 3;
  int grp = i / 48;
  int rem = i - grp * 48;
  int nblk = grp * 6 + (rem % 6);
  int mblk = (xcd << 3) + rem / 6;
  int m0 = mblk * BM;
  int n0 = nblk * BN;

  constexpr int MT = (BN == 128) ? 4 : 2;
  constexpr int NT = 4;
  int wm = (BN == 128) ? (wave & 1) * 64 : wave * 32;
  int wn = (BN == 128) ? (wave >> 1) * 64 : 0;

  floatx4 acc[MT][NT];
#pragma unroll
  for (int mi = 0; mi < MT; mi++)
#pragma unroll
    for (int ni = 0; ni < NT; ni++) acc[mi][ni] = (floatx4){0.f, 0.f, 0.f, 0.f};

  int srow = tid >> 2;
  int scol = (tid & 3) * 8;
  const u16* Ag0 = A + (size_t)(m0 + srow) * lda + scol;
  const u16* Ag1 = A + (size_t)(m0 + 64 + srow) * lda + scol;
  const u16* Bg0 = BT + (size_t)(n0 + srow) * K + scol;
  u16* AsW0 = As + wave * 512;
  u16* AsW1 = As + 2048 + wave * 512;
  u16* BsW0 = Bs + wave * 512;

  for (int k0 = 0; k0 < K; k0 += BK) {
    g2l16(Ag0 + k0, AsW0);
    g2l16(Ag1 + k0, AsW1);
    g2l16(Bg0 + k0, BsW0);
    if constexpr (BN == 128) {
      const u16* Bg1 = BT + (size_t)(n0 + 64 + srow) * K + scol;
      g2l16(Bg1 + k0, Bs + 2048 + wave * 512);
    }
    __syncthreads();
    short8 af[MT], bfr[NT];
#pragma unroll
    for (int mi = 0; mi < MT; mi++)
      af[mi] = *(const short8*)&As[(wm + mi * 16 + l15) * BK + quad * 8];
#pragma unroll
    for (int ni = 0; ni < NT; ni++)
      bfr[ni] = *(const short8*)&Bs[(wn + ni * 16 + l15) * BK + quad * 8];
#pragma unroll
    for (int mi = 0; mi < MT; mi++)
#pragma unroll
      for (int ni = 0; ni < NT; ni++)
        acc[mi][ni] = __builtin_amdgcn_mfma_f32_16x16x32_bf16(
            af[mi], bfr[ni], acc[mi][ni], 0, 0, 0);
    __syncthreads();
  }

#pragma unroll
  for (int mi = 0; mi < MT; mi++) {
#pragma unroll
    for (int ni = 0; ni < NT; ni++) {
      int col = n0 + wn + ni * 16 + l15;
      float bv = bias[col];
#pragma unroll
      for (int r = 0; r < 4; r++) {
        int row = m0 + wm + mi * 16 + quad * 4 + r;
        float v = acc[mi][ni][r] + bv;
        if (act == 1) v = 0.5f * v * (1.0f + erff(v * 0.70710678118654752f));
        if (c_fp32) ((float*)Cv)[(size_t)row * N + col] = v;
        else        ((u16*)Cv)[(size_t)row * N + col] = f2bf(v);
      }
    }
  }
}

// ------------- flash-style MFMA attention on fused qkv [M,2304] --------------
// q=cols 0..767, k=768..1535, v=1536..2303. ctx written IN-PLACE into q slot.
__global__ __launch_bounds__(256) void attn_kernel(u16* __restrict__ qkv) {
  __shared__ __align__(16) u16 Qs[64][72];
  __shared__ __align__(16) u16 Ks[64][72];
  __shared__ __align__(16) u16 Vt[64][72];   // [d][key]
  __shared__ __align__(16) u16 Ps[4][16][72];

  const int LD = 2304;
  int bh = blockIdx.x;  // 0..191
  int b = bh / 12;
  int h = bh - b * 12;
  int q0 = blockIdx.y * 64;
  size_t base = (size_t)b * 512 * LD + (size_t)h * 64;
  const u16* qg = qkv + base;
  const u16* kg = qkv + base + 768;
  const u16* vg = qkv + base + 1536;
  int tid = threadIdx.x;
  int wave = tid >> 6;
  int lane = tid & 63;
  int l15 = lane & 15;
  int quad = lane >> 4;

  int srow = tid >> 2;
  int sd = (tid & 3) * 16;

  {
    const u16* qp = qg + (size_t)(q0 + srow) * LD + sd;
    *(int4*)&Qs[srow][sd]     = *(const int4*)qp;
    *(int4*)&Qs[srow][sd + 8] = *(const int4*)(qp + 8);
  }
  __syncthreads();

  short8 aQ[2];
#pragma unroll
  for (int k = 0; k < 2; k++)
    aQ[k] = *(const short8*)&Qs[16 * wave + l15][k * 32 + quad * 8];

  floatx4 O[4];
  float m_r[4], l_r[4];
#pragma unroll
  for (int nt = 0; nt < 4; nt++) O[nt] = (floatx4){0.f, 0.f, 0.f, 0.f};
#pragma unroll
  for (int r = 0; r < 4; r++) { m_r[r] = -1e30f; l_r[r] = 0.f; }

  const float cst = 0.18033688011112042f;  // (1/8) * log2(e)

  for (int c = 0; c < 8; c++) {
    const u16* kp = kg + (size_t)(c * 64 + srow) * LD + sd;
    const u16* vp = vg + (size_t)(c * 64 + srow) * LD + sd;
    int4 kv0 = *(const int4*)kp;
    int4 kv1 = *(const int4*)(kp + 8);
    int4 vv0 = *(const int4*)vp;
    int4 vv1 = *(const int4*)(vp + 8);
    __syncthreads();
    *(int4*)&Ks[srow][sd]     = kv0;
    *(int4*)&Ks[srow][sd + 8] = kv1;
    {
      u16 tv[16];
      *(int4*)tv = vv0;
      *(int4*)(tv + 8) = vv1;
#pragma unroll
      for (int j = 0; j < 16; j++) Vt[sd + j][srow] = tv[j];
    }
    __syncthreads();

    floatx4 S[4];
#pragma unroll
    for (int nt = 0; nt < 4; nt++) {
      floatx4 s = {0.f, 0.f, 0.f, 0.f};
      short8 bK0 = *(const short8*)&Ks[nt * 16 + l15][quad * 8];
      short8 bK1 = *(const short8*)&Ks[nt * 16 + l15][32 + quad * 8];
      s = __builtin_amdgcn_mfma_f32_16x16x32_bf16(aQ[0], bK0, s, 0, 0, 0);
      s = __builtin_amdgcn_mfma_f32_16x16x32_bf16(aQ[1], bK1, s, 0, 0, 0);
      S[nt] = s;
    }

#pragma unroll
    for (int r = 0; r < 4; r++) {
      float s0 = S[0][r] * cst, s1 = S[1][r] * cst;
      float s2 = S[2][r] * cst, s3 = S[3][r] * cst;
      float mr = fmaxf(fmaxf(s0, s1), fmaxf(s2, s3));
#pragma unroll
      for (int off = 1; off < 16; off <<= 1) mr = fmaxf(mr, __shfl_xor(mr, off, 16));
      float m_new = fmaxf(m_r[r], mr);
      float alpha = exp2f(m_r[r] - m_new);
      m_r[r] = m_new;
      float p0 = exp2f(s0 - m_new), p1 = exp2f(s1 - m_new);
      float p2 = exp2f(s2 - m_new), p3 = exp2f(s3 - m_new);
      S[0][r] = p0; S[1][r] = p1; S[2][r] = p2; S[3][r] = p3;
      float sum = p0 + p1 + p2 + p3;
#pragma unroll
      for (int off = 1; off < 16; off <<= 1) sum += __shfl_xor(sum, off, 16);
      l_r[r] = l_r[r] * alpha + sum;
      O[0][r] *= alpha; O[1][r] *= alpha; O[2][r] *= alpha; O[3][r] *= alpha;
    }

#pragma unroll
    for (int nt = 0; nt < 4; nt++)
#pragma unroll
      for (int r = 0; r < 4; r++)
        Ps[wave][quad * 4 + r][nt * 16 + l15] = f2bf(S[nt][r]);

    short8 aP[2];
#pragma unroll
    for (int k = 0; k < 2; k++)
      aP[k] = *(const short8*)&Ps[wave][l15][k * 32 + quad * 8];

#pragma unroll
    for (int nt = 0; nt < 4; nt++) {
      short8 bV0 = *(const short8*)&Vt[nt * 16 + l15][quad * 8];
      short8 bV1 = *(const short8*)&Vt[nt * 16 + l15][32 + quad * 8];
      O[nt] = __builtin_amdgcn_mfma_f32_16x16x32_bf16(aP[0], bV0, O[nt], 0, 0, 0);
      O[nt] = __builtin_amdgcn_mfma_f32_16x16x32_bf16(aP[1], bV1, O[nt], 0, 0, 0);
    }
  }

#pragma unroll
  for (int r = 0; r < 4; r++) {
    float inv = 1.0f / l_r[r];
    int row = q0 + 16 * wave + quad * 4 + r;
    u16* cp = qkv + base + (size_t)row * LD;
#pragma unroll
    for (int nt = 0; nt < 4; nt++)
      cp[nt * 16 + l15] = f2bf(O[nt][r] * inv);
  }
}

// ------------- LN1: out_bf16 = LN(a_bf16 + r_f32) ----------------------------
__global__ __launch_bounds__(256) void ln1_kernel(
    const u16* __restrict__ a, const float* __restrict__ r,
    const float* __restrict__ g, const float* __restrict__ bb,
    u16* __restrict__ out) {
  int row = blockIdx.x;
  int tid = threadIdx.x;
  __shared__ float red[4];
  const u16* ap = a + (size_t)row * 768;
  const float* rp = r + (size_t)row * 768;
  float x0 = bits2f(ap[tid]) + rp[tid];
  float x1 = bits2f(ap[tid + 256]) + rp[tid + 256];
  float x2 = bits2f(ap[tid + 512]) + rp[tid + 512];
  float s = x0 + x1 + x2;
#pragma unroll
  for (int off = 32; off > 0; off >>= 1) s += __shfl_xor(s, off, 64);
  if ((tid & 63) == 0) red[tid >> 6] = s;
  __syncthreads();
  float mu = (red[0] + red[1] + red[2] + red[3]) * (1.0f / 768.0f);
  float d0 = x0 - mu, d1 = x1 - mu, d2 = x2 - mu;
  float vs = d0 * d0 + d1 * d1 + d2 * d2;
#pragma unroll
  for (int off = 32; off > 0; off >>= 1) vs += __shfl_xor(vs, off, 64);
  __syncthreads();
  if ((tid & 63) == 0) red[tid >> 6] = vs;
  __syncthreads();
  float var = (red[0] + red[1] + red[2] + red[3]) * (1.0f / 768.0f);
  float rstd = rsqrtf(var + 1e-12f);
  size_t o = (size_t)row * 768;
  out[o + tid]       = f2bf(d0 * rstd * g[tid] + bb[tid]);
  out[o + tid + 256] = f2bf(d1 * rstd * g[tid + 256] + bb[tid + 256]);
  out[o + tid + 512] = f2bf(d2 * rstd * g[tid + 512] + bb[tid + 512]);
}

// ------------- LN2: out_f32 = LN(a_f32 + r_bf16), in-place safe --------------
__global__ __launch_bounds__(256) void ln2_kernel(
    const float* __restrict__ a, const u16* __restrict__ r,
    const float* __restrict__ g, const float* __restrict__ bb,
    float* __restrict__ out) {
  int row = blockIdx.x;
  int tid = threadIdx.x;
  __shared__ float red[4];
  const float* ap = a + (size_t)row * 768;
  const u16* rp = r + (size_t)row * 768;
  float x0 = ap[tid] + bits2f(rp[tid]);
  float x1 = ap[tid + 256] + bits2f(rp[tid + 256]);
  float x2 = ap[tid + 512] + bits2f(rp[tid + 512]);
  float s = x0 + x1 + x2;
#pragma unroll
  for (int off = 32; off > 0; off >>= 1) s += __shfl_xor(s, off, 64);
  if ((tid & 63) == 0) red[tid >> 6] = s;
  __syncthreads();
  float mu = (red[0] + red[1] + red[2] + red[3]) * (1.0f / 768.0f);
  float d0 = x0 - mu, d1 = x1 - mu, d2 = x2 - mu;
  float vs = d0 * d0 + d1 * d1 + d2 * d2;
#pragma unroll
  for (int off = 32; off > 0; off >>= 1) vs += __shfl_xor(vs, off, 64);
  __syncthreads();
  if ((tid & 63) == 0) red[tid >> 6] = vs;
  __syncthreads();
  float var = (red[0] + red[1] + red[2] + red[3]) * (1.0f / 768.0f);
  float rstd = rsqrtf(var + 1e-12f);
  size_t o = (size_t)row * 768;
  out[o + tid]       = d0 * rstd * g[tid] + bb[tid];
  out[o + tid + 256] = d1 * rstd * g[tid + 256] + bb[tid + 256];
  out[o + tid + 512] = d2 * rstd * g[tid + 512] + bb[tid + 512];
}

extern "C" void kernel_launch(void* const* d_in, const int* in_sizes, int n_in,
                              void* d_out, int out_size, void* d_ws, size_t ws_size,
                              hipStream_t stream) {
  (void)in_sizes; (void)n_in; (void)out_size; (void)ws_size;
  const float* x    = (const float*)d_in[0];
  const float* Wq   = (const float*)d_in[1];
  const float* bq   = (const float*)d_in[2];
  const float* Wk   = (const float*)d_in[3];
  const float* bk   = (const float*)d_in[4];
  const float* Wv   = (const float*)d_in[5];
  const float* bv   = (const float*)d_in[6];
  const float* Wo   = (const float*)d_in[7];
  const float* bo   = (const float*)d_in[8];
  const float* ln1g = (const float*)d_in[9];
  const float* ln1b = (const float*)d_in[10];
  const float* W1   = (const float*)d_in[11];
  const float* b1   = (const float*)d_in[12];
  const float* W2   = (const float*)d_in[13];
  const float* b2   = (const float*)d_in[14];
  const float* ln2g = (const float*)d_in[15];
  const float* ln2b = (const float*)d_in[16];

  const int M = 16 * 512, H = 768, FF = 3072;
  const size_t MH = (size_t)M * H;
  const size_t HH = (size_t)H * H;

  u16* ws    = (u16*)d_ws;
  u16* qkv   = ws;
  u16* xb    = ws + 3 * MH;
  u16* aob   = xb;             // aob overwrites xb (dead after QKV GEMM)
  u16* ffn1  = ws;             // [0,4MH): qkv+aob both dead by FFN1
  u16* hb    = ws + 4 * MH;
  u16* WTqkv = ws + 5 * MH;
  u16* WTo   = WTqkv + 3 * HH;
  u16* WT1   = WTqkv + 4 * HH;
  u16* WT2   = WTqkv;          // 4HH, reused after QKV GEMM
  float* biasqkv = (float*)(WT1 + 4 * HH);
  float* outf = (float*)d_out;

  dim3 tb(256);
  prep_kernel<<<dim3(7689), tb, 0, stream>>>(x, xb, bq, bk, bv, biasqkv,
                                             Wq, Wk, Wv, Wo, W1,
                                             WTqkv, WTo, WT1);

  // fused QKV: [M,2304] = xb[M,768] @ WTqkv^T
  gemm_m97<128><<<dim3(2304 / 128, M / 128), tb, 0, stream>>>(
      xb, H, WTqkv, biasqkv, qkv, M, 2304, H, 0, 0);

  attn_kernel<<<dim3(192, 8), tb, 0, stream>>>(qkv);

  // attn out: aob[M,768] = ctx(q-slot of qkv, lda=2304) @ WTo^T
  gemm_m97<64><<<dim3(H / 64, M / 128), tb, 0, stream>>>(
      qkv, 2304, WTo, bo, aob, M, H, H, 0, 0);
  ln1_kernel<<<dim3(M), tb, 0, stream>>>(aob, x, ln1g, ln1b, hb);

  transpose_k<<<dim3(H / 32, FF / 32), tb, 0, stream>>>(W2, WT2, FF, H);

  gemm_m97<128><<<dim3(FF / 128, M / 128), tb, 0, stream>>>(
      hb, H, WT1, b1, ffn1, M, FF, H, 1, 0);
  gemm_m97<64><<<dim3(H / 64, M / 128), tb, 0, stream>>>(
      ffn1, FF, WT2, b2, outf, M, H, FF, 0, 1);
  ln2_kernel<<<dim3(M), tb, 0, stream>>>(outf, hb, ln2g, ln2b, outf);
}

// Round 6
// 398.476 us; speedup vs baseline: 3.1345x; 1.0321x over previous
//
#include <hip/hip_runtime.h>

typedef short short8 __attribute__((ext_vector_type(8)));
typedef float floatx4 __attribute__((ext_vector_type(4)));
typedef unsigned short u16;
typedef unsigned int u32;

__device__ __forceinline__ float bits2f(u16 u) {
  union { unsigned int i; float f; } w;
  w.i = ((unsigned int)u) << 16;
  return w.f;
}

__device__ __forceinline__ u16 f2bf(float f) {
  union { float f; unsigned int i; } w;
  w.f = f;
  unsigned int x = w.i;
  unsigned int r = (x + 0x7FFFu + ((x >> 16) & 1u)) >> 16;  // RNE
  return (u16)r;
}

// tanh-form GELU: 0.5x(1+tanh(sqrt(2/pi)(x+0.044715x^3))) = x*sigmoid(t),
// t = 2*sqrt(2/pi)*(x+0.044715x^3). Max abs dev from exact GELU ~3e-4.
__device__ __forceinline__ float gelu_f(float x) {
  float t = x * (1.5957691216057308f + 0.07135481283247914f * x * x);
  return x / (1.0f + __expf(-t));
}

// async global->LDS, 16 B per lane; lds dest = wave-uniform base + lane*16
__device__ __forceinline__ void g2l16(const u16* g, u16* l) {
  __builtin_amdgcn_global_load_lds(
      (const __attribute__((address_space(1))) u32*)(const void*)g,
      (__attribute__((address_space(3))) u32*)(void*)l, 16, 0, 0);
}

// ------------- fused prep: cvt x->bf16, pack qkv bias, 5 weight transposes ---
__global__ __launch_bounds__(256) void prep_kernel(
    const float* __restrict__ x, u16* __restrict__ xb,
    const float* __restrict__ bq, const float* __restrict__ bk,
    const float* __restrict__ bv, float* __restrict__ biasqkv,
    const float* __restrict__ Wq, const float* __restrict__ Wk,
    const float* __restrict__ Wv, const float* __restrict__ Wo,
    const float* __restrict__ W1,
    u16* __restrict__ WTqkv, u16* __restrict__ WTo, u16* __restrict__ WT1) {
  __shared__ float tile[32][33];
  int bid = blockIdx.x;
  int tid = threadIdx.x;
  if (bid < 3072) {  // cvt: 3072*256*8 == 16*512*768
    int i = bid * 256 + tid;
    const float4* p = (const float4*)x + (size_t)i * 2;
    float4 a = p[0], b = p[1];
    u16 t[8] = {f2bf(a.x), f2bf(a.y), f2bf(a.z), f2bf(a.w),
                f2bf(b.x), f2bf(b.y), f2bf(b.z), f2bf(b.w)};
    *(int4*)(xb + (size_t)i * 8) = *(const int4*)t;
    return;
  }
  if (bid < 3081) {  // bias pack
    int i = (bid - 3072) * 256 + tid;
    biasqkv[i] = (i < 768) ? bq[i] : (i < 1536 ? bk[i - 768] : bv[i - 1536]);
    return;
  }
  const float* W;
  u16* WT;
  int K, N, bx, by;
  if (bid < 5385) {  // 4 square transposes, 576 blocks each
    int s = bid - 3081;
    int wsel = s / 576;
    int r = s - wsel * 576;
    K = 768; N = 768; bx = r % 24; by = r / 24;
    if (wsel == 0)      { W = Wq; WT = WTqkv; }
    else if (wsel == 1) { W = Wk; WT = WTqkv + 768 * 768; }
    else if (wsel == 2) { W = Wv; WT = WTqkv + 2 * 768 * 768; }
    else                { W = Wo; WT = WTo; }
  } else {  // W1 [768,3072] -> WT1 [3072,768]
    int r = bid - 5385;
    K = 768; N = 3072; bx = r % 96; by = r / 96;
    W = W1; WT = WT1;
  }
  int tx = tid & 31, ty = tid >> 5;
  int n0 = bx * 32, k0 = by * 32;
#pragma unroll
  for (int i = 0; i < 4; i++)
    tile[ty + i * 8][tx] = W[(size_t)(k0 + ty + i * 8) * N + n0 + tx];
  __syncthreads();
#pragma unroll
  for (int i = 0; i < 4; i++)
    WT[(size_t)(n0 + ty + i * 8) * K + k0 + tx] = f2bf(tile[tx][ty + i * 8]);
}

// ------------- standalone transpose (for W2; WT2 aliases WTqkv) --------------
__global__ __launch_bounds__(256) void transpose_k(const float* __restrict__ W,
                                                   u16* __restrict__ WT,
                                                   int K, int N) {
  __shared__ float tile[32][33];
  int tx = threadIdx.x & 31;
  int ty = threadIdx.x >> 5;
  int n0 = blockIdx.x * 32;
  int k0 = blockIdx.y * 32;
#pragma unroll
  for (int i = 0; i < 4; i++)
    tile[ty + i * 8][tx] = W[(size_t)(k0 + ty + i * 8) * N + n0 + tx];
  __syncthreads();
#pragma unroll
  for (int i = 0; i < 4; i++)
    WT[(size_t)(n0 + ty + i * 8) * K + k0 + tx] = f2bf(tile[tx][ty + i * 8]);
}

// ------------- dbuf m97 GEMM: C[M,N] = A[M,K](lda) @ BT[N,K]^T + bias --------
// BM=128, BK=32, 256 threads, double-buffered LDS, ONE barrier per K-iter:
// barrier drains tile-k DMA (in flight during iter k-1's compute), then tile-
// k+1 DMA is issued into the other buffer before computing on tile k.
// XCD swizzle: requires gridDim.y==64, gridDim.x%6==0.
template <int BN>
__global__ __launch_bounds__(256) void gemm_m97(
    const u16* __restrict__ A, int lda, const u16* __restrict__ BT,
    const float* __restrict__ bias, void* __restrict__ Cv,
    int M, int N, int K, int act, int c_fp32) {
  constexpr int BM = 128, BK = 32;
  constexpr int ASZ = BM * BK, BSZ = BN * BK;
  __shared__ __align__(16) u16 As[2 * ASZ];
  __shared__ __align__(16) u16 Bs[2 * BSZ];
  int tid = threadIdx.x;
  int wave = tid >> 6;
  int lane = tid & 63;
  int l15 = lane & 15;
  int quad = lane >> 4;

  // XCD-aware swizzle: lin%8 -> XCD band of 8 m-blocks; 8m x 6n supertiles
  int nb = gridDim.x;
  int lin = blockIdx.y * nb + blockIdx.x;
  int xcd = lin & 7;
  int i = lin >> 3;
  int grp = i / 48;
  int rem = i - grp * 48;
  int nblk = grp * 6 + (rem % 6);
  int mblk = (xcd << 3) + rem / 6;
  int m0 = mblk * BM;
  int n0 = nblk * BN;

  constexpr int MT = (BN == 128) ? 4 : 2;
  constexpr int NT = 4;
  int wm = (BN == 128) ? (wave & 1) * 64 : wave * 32;
  int wn = (BN == 128) ? (wave >> 1) * 64 : 0;

  floatx4 acc[MT][NT];
#pragma unroll
  for (int mi = 0; mi < MT; mi++)
#pragma unroll
    for (int ni = 0; ni < NT; ni++) acc[mi][ni] = (floatx4){0.f, 0.f, 0.f, 0.f};

  int srow = tid >> 2;
  int scol = (tid & 3) * 8;
  const u16* Ag0 = A + (size_t)(m0 + srow) * lda + scol;
  const u16* Ag1 = A + (size_t)(m0 + 64 + srow) * lda + scol;
  const u16* Bg0 = BT + (size_t)(n0 + srow) * K + scol;
  const u16* Bg1 = BT + (size_t)(n0 + 64 + srow) * K + scol;  // BN==128 only
  int woff = wave * 512;

  // stage tile k into buffer buf
  auto stage = [&](int k0, int buf) {
    u16* Ab = As + buf * ASZ;
    u16* Bb = Bs + buf * BSZ;
    g2l16(Ag0 + k0, Ab + woff);
    g2l16(Ag1 + k0, Ab + 2048 + woff);
    g2l16(Bg0 + k0, Bb + woff);
    if constexpr (BN == 128) g2l16(Bg1 + k0, Bb + 2048 + woff);
  };

  int nk = K / BK;
  stage(0, 0);
  for (int k = 0; k < nk; k++) {
    int cur = k & 1;
    __syncthreads();                       // tile-k DMA done; prev reads done
    if (k + 1 < nk) stage((k + 1) * BK, cur ^ 1);
    const u16* Ab = As + cur * ASZ;
    const u16* Bb = Bs + cur * BSZ;
    short8 af[MT], bfr[NT];
#pragma unroll
    for (int mi = 0; mi < MT; mi++)
      af[mi] = *(const short8*)&Ab[(wm + mi * 16 + l15) * BK + quad * 8];
#pragma unroll
    for (int ni = 0; ni < NT; ni++)
      bfr[ni] = *(const short8*)&Bb[(wn + ni * 16 + l15) * BK + quad * 8];
#pragma unroll
    for (int mi = 0; mi < MT; mi++)
#pragma unroll
      for (int ni = 0; ni < NT; ni++)
        acc[mi][ni] = __builtin_amdgcn_mfma_f32_16x16x32_bf16(
            af[mi], bfr[ni], acc[mi][ni], 0, 0, 0);
  }

#pragma unroll
  for (int mi = 0; mi < MT; mi++) {
#pragma unroll
    for (int ni = 0; ni < NT; ni++) {
      int col = n0 + wn + ni * 16 + l15;
      float bv = bias[col];
#pragma unroll
      for (int r = 0; r < 4; r++) {
        int row = m0 + wm + mi * 16 + quad * 4 + r;
        float v = acc[mi][ni][r] + bv;
        if (act == 1) v = gelu_f(v);
        if (c_fp32) ((float*)Cv)[(size_t)row * N + col] = v;
        else        ((u16*)Cv)[(size_t)row * N + col] = f2bf(v);
      }
    }
  }
}

// ------------- flash-style MFMA attention on fused qkv [M,2304] --------------
__global__ __launch_bounds__(256) void attn_kernel(u16* __restrict__ qkv) {
  __shared__ __align__(16) u16 Qs[64][72];
  __shared__ __align__(16) u16 Ks[64][72];
  __shared__ __align__(16) u16 Vt[64][72];   // [d][key]
  __shared__ __align__(16) u16 Ps[4][16][72];

  const int LD = 2304;
  int bh = blockIdx.x;  // 0..191
  int b = bh / 12;
  int h = bh - b * 12;
  int q0 = blockIdx.y * 64;
  size_t base = (size_t)b * 512 * LD + (size_t)h * 64;
  const u16* qg = qkv + base;
  const u16* kg = qkv + base + 768;
  const u16* vg = qkv + base + 1536;
  int tid = threadIdx.x;
  int wave = tid >> 6;
  int lane = tid & 63;
  int l15 = lane & 15;
  int quad = lane >> 4;

  int srow = tid >> 2;
  int sd = (tid & 3) * 16;

  {
    const u16* qp = qg + (size_t)(q0 + srow) * LD + sd;
    *(int4*)&Qs[srow][sd]     = *(const int4*)qp;
    *(int4*)&Qs[srow][sd + 8] = *(const int4*)(qp + 8);
  }
  __syncthreads();

  short8 aQ[2];
#pragma unroll
  for (int k = 0; k < 2; k++)
    aQ[k] = *(const short8*)&Qs[16 * wave + l15][k * 32 + quad * 8];

  floatx4 O[4];
  float m_r[4], l_r[4];
#pragma unroll
  for (int nt = 0; nt < 4; nt++) O[nt] = (floatx4){0.f, 0.f, 0.f, 0.f};
#pragma unroll
  for (int r = 0; r < 4; r++) { m_r[r] = -1e30f; l_r[r] = 0.f; }

  const float cst = 0.18033688011112042f;  // (1/8) * log2(e)

  for (int c = 0; c < 8; c++) {
    const u16* kp = kg + (size_t)(c * 64 + srow) * LD + sd;
    const u16* vp = vg + (size_t)(c * 64 + srow) * LD + sd;
    int4 kv0 = *(const int4*)kp;
    int4 kv1 = *(const int4*)(kp + 8);
    int4 vv0 = *(const int4*)vp;
    int4 vv1 = *(const int4*)(vp + 8);
    __syncthreads();
    *(int4*)&Ks[srow][sd]     = kv0;
    *(int4*)&Ks[srow][sd + 8] = kv1;
    {
      u16 tv[16];
      *(int4*)tv = vv0;
      *(int4*)(tv + 8) = vv1;
#pragma unroll
      for (int j = 0; j < 16; j++) Vt[sd + j][srow] = tv[j];
    }
    __syncthreads();

    floatx4 S[4];
#pragma unroll
    for (int nt = 0; nt < 4; nt++) {
      floatx4 s = {0.f, 0.f, 0.f, 0.f};
      short8 bK0 = *(const short8*)&Ks[nt * 16 + l15][quad * 8];
      short8 bK1 = *(const short8*)&Ks[nt * 16 + l15][32 + quad * 8];
      s = __builtin_amdgcn_mfma_f32_16x16x32_bf16(aQ[0], bK0, s, 0, 0, 0);
      s = __builtin_amdgcn_mfma_f32_16x16x32_bf16(aQ[1], bK1, s, 0, 0, 0);
      S[nt] = s;
    }

#pragma unroll
    for (int r = 0; r < 4; r++) {
      float s0 = S[0][r] * cst, s1 = S[1][r] * cst;
      float s2 = S[2][r] * cst, s3 = S[3][r] * cst;
      float mr = fmaxf(fmaxf(s0, s1), fmaxf(s2, s3));
#pragma unroll
      for (int off = 1; off < 16; off <<= 1) mr = fmaxf(mr, __shfl_xor(mr, off, 16));
      float m_new = fmaxf(m_r[r], mr);
      float alpha = exp2f(m_r[r] - m_new);
      m_r[r] = m_new;
      float p0 = exp2f(s0 - m_new), p1 = exp2f(s1 - m_new);
      float p2 = exp2f(s2 - m_new), p3 = exp2f(s3 - m_new);
      S[0][r] = p0; S[1][r] = p1; S[2][r] = p2; S[3][r] = p3;
      float sum = p0 + p1 + p2 + p3;
#pragma unroll
      for (int off = 1; off < 16; off <<= 1) sum += __shfl_xor(sum, off, 16);
      l_r[r] = l_r[r] * alpha + sum;
      O[0][r] *= alpha; O[1][r] *= alpha; O[2][r] *= alpha; O[3][r] *= alpha;
    }

#pragma unroll
    for (int nt = 0; nt < 4; nt++)
#pragma unroll
      for (int r = 0; r < 4; r++)
        Ps[wave][quad * 4 + r][nt * 16 + l15] = f2bf(S[nt][r]);

    short8 aP[2];
#pragma unroll
    for (int k = 0; k < 2; k++)
      aP[k] = *(const short8*)&Ps[wave][l15][k * 32 + quad * 8];

#pragma unroll
    for (int nt = 0; nt < 4; nt++) {
      short8 bV0 = *(const short8*)&Vt[nt * 16 + l15][quad * 8];
      short8 bV1 = *(const short8*)&Vt[nt * 16 + l15][32 + quad * 8];
      O[nt] = __builtin_amdgcn_mfma_f32_16x16x32_bf16(aP[0], bV0, O[nt], 0, 0, 0);
      O[nt] = __builtin_amdgcn_mfma_f32_16x16x32_bf16(aP[1], bV1, O[nt], 0, 0, 0);
    }
  }

#pragma unroll
  for (int r = 0; r < 4; r++) {
    float inv = 1.0f / l_r[r];
    int row = q0 + 16 * wave + quad * 4 + r;
    u16* cp = qkv + base + (size_t)row * LD;
#pragma unroll
    for (int nt = 0; nt < 4; nt++)
      cp[nt * 16 + l15] = f2bf(O[nt][r] * inv);
  }
}

// ------------- LN1: out_bf16 = LN(a_bf16 + r_f32) ----------------------------
__global__ __launch_bounds__(256) void ln1_kernel(
    const u16* __restrict__ a, const float* __restrict__ r,
    const float* __restrict__ g, const float* __restrict__ bb,
    u16* __restrict__ out) {
  int row = blockIdx.x;
  int tid = threadIdx.x;
  __shared__ float red[4];
  const u16* ap = a + (size_t)row * 768;
  const float* rp = r + (size_t)row * 768;
  float x0 = bits2f(ap[tid]) + rp[tid];
  float x1 = bits2f(ap[tid + 256]) + rp[tid + 256];
  float x2 = bits2f(ap[tid + 512]) + rp[tid + 512];
  float s = x0 + x1 + x2;
#pragma unroll
  for (int off = 32; off > 0; off >>= 1) s += __shfl_xor(s, off, 64);
  if ((tid & 63) == 0) red[tid >> 6] = s;
  __syncthreads();
  float mu = (red[0] + red[1] + red[2] + red[3]) * (1.0f / 768.0f);
  float d0 = x0 - mu, d1 = x1 - mu, d2 = x2 - mu;
  float vs = d0 * d0 + d1 * d1 + d2 * d2;
#pragma unroll
  for (int off = 32; off > 0; off >>= 1) vs += __shfl_xor(vs, off, 64);
  __syncthreads();
  if ((tid & 63) == 0) red[tid >> 6] = vs;
  __syncthreads();
  float var = (red[0] + red[1] + red[2] + red[3]) * (1.0f / 768.0f);
  float rstd = rsqrtf(var + 1e-12f);
  size_t o = (size_t)row * 768;
  out[o + tid]       = f2bf(d0 * rstd * g[tid] + bb[tid]);
  out[o + tid + 256] = f2bf(d1 * rstd * g[tid + 256] + bb[tid + 256]);
  out[o + tid + 512] = f2bf(d2 * rstd * g[tid + 512] + bb[tid + 512]);
}

// ------------- LN2: out_f32 = LN(a_f32 + r_bf16), in-place safe --------------
__global__ __launch_bounds__(256) void ln2_kernel(
    const float* __restrict__ a, const u16* __restrict__ r,
    const float* __restrict__ g, const float* __restrict__ bb,
    float* __restrict__ out) {
  int row = blockIdx.x;
  int tid = threadIdx.x;
  __shared__ float red[4];
  const float* ap = a + (size_t)row * 768;
  const u16* rp = r + (size_t)row * 768;
  float x0 = ap[tid] + bits2f(rp[tid]);
  float x1 = ap[tid + 256] + bits2f(rp[tid + 256]);
  float x2 = ap[tid + 512] + bits2f(rp[tid + 512]);
  float s = x0 + x1 + x2;
#pragma unroll
  for (int off = 32; off > 0; off >>= 1) s += __shfl_xor(s, off, 64);
  if ((tid & 63) == 0) red[tid >> 6] = s;
  __syncthreads();
  float mu = (red[0] + red[1] + red[2] + red[3]) * (1.0f / 768.0f);
  float d0 = x0 - mu, d1 = x1 - mu, d2 = x2 - mu;
  float vs = d0 * d0 + d1 * d1 + d2 * d2;
#pragma unroll
  for (int off = 32; off > 0; off >>= 1) vs += __shfl_xor(vs, off, 64);
  __syncthreads();
  if ((tid & 63) == 0) red[tid >> 6] = vs;
  __syncthreads();
  float var = (red[0] + red[1] + red[2] + red[3]) * (1.0f / 768.0f);
  float rstd = rsqrtf(var + 1e-12f);
  size_t o = (size_t)row * 768;
  out[o + tid]       = d0 * rstd * g[tid] + bb[tid];
  out[o + tid + 256] = d1 * rstd * g[tid + 256] + bb[tid + 256];
  out[o + tid + 512] = d2 * rstd * g[tid + 512] + bb[tid + 512];
}

extern "C" void kernel_launch(void* const* d_in, const int* in_sizes, int n_in,
                              void* d_out, int out_size, void* d_ws, size_t ws_size,
                              hipStream_t stream) {
  (void)in_sizes; (void)n_in; (void)out_size; (void)ws_size;
  const float* x    = (const float*)d_in[0];
  const float* Wq   = (const float*)d_in[1];
  const float* bq   = (const float*)d_in[2];
  const float* Wk   = (const float*)d_in[3];
  const float* bk   = (const float*)d_in[4];
  const float* Wv   = (const float*)d_in[5];
  const float* bv   = (const float*)d_in[6];
  const float* Wo   = (const float*)d_in[7];
  const float* bo   = (const float*)d_in[8];
  const float* ln1g = (const float*)d_in[9];
  const float* ln1b = (const float*)d_in[10];
  const float* W1   = (const float*)d_in[11];
  const float* b1   = (const float*)d_in[12];
  const float* W2   = (const float*)d_in[13];
  const float* b2   = (const float*)d_in[14];
  const float* ln2g = (const float*)d_in[15];
  const float* ln2b = (const float*)d_in[16];

  const int M = 16 * 512, H = 768, FF = 3072;
  const size_t MH = (size_t)M * H;
  const size_t HH = (size_t)H * H;

  u16* ws    = (u16*)d_ws;
  u16* qkv   = ws;
  u16* xb    = ws + 3 * MH;
  u16* aob   = xb;             // aob overwrites xb (dead after QKV GEMM)
  u16* ffn1  = ws;             // [0,4MH): qkv+aob both dead by FFN1
  u16* hb    = ws + 4 * MH;
  u16* WTqkv = ws + 5 * MH;
  u16* WTo   = WTqkv + 3 * HH;
  u16* WT1   = WTqkv + 4 * HH;
  u16* WT2   = WTqkv;          // 4HH, reused after QKV GEMM
  float* biasqkv = (float*)(WT1 + 4 * HH);
  float* outf = (float*)d_out;

  dim3 tb(256);
  prep_kernel<<<dim3(7689), tb, 0, stream>>>(x, xb, bq, bk, bv, biasqkv,
                                             Wq, Wk, Wv, Wo, W1,
                                             WTqkv, WTo, WT1);

  // fused QKV: [M,2304] = xb[M,768] @ WTqkv^T
  gemm_m97<128><<<dim3(2304 / 128, M / 128), tb, 0, stream>>>(
      xb, H, WTqkv, biasqkv, qkv, M, 2304, H, 0, 0);

  attn_kernel<<<dim3(192, 8), tb, 0, stream>>>(qkv);

  // attn out: aob[M,768] = ctx(q-slot of qkv, lda=2304) @ WTo^T
  gemm_m97<64><<<dim3(H / 64, M / 128), tb, 0, stream>>>(
      qkv, 2304, WTo, bo, aob, M, H, H, 0, 0);
  ln1_kernel<<<dim3(M), tb, 0, stream>>>(aob, x, ln1g, ln1b, hb);

  transpose_k<<<dim3(H / 32, FF / 32), tb, 0, stream>>>(W2, WT2, FF, H);

  gemm_m97<128><<<dim3(FF / 128, M / 128), tb, 0, stream>>>(
      hb, H, WT1, b1, ffn1, M, FF, H, 1, 0);
  gemm_m97<64><<<dim3(H / 64, M / 128), tb, 0, stream>>>(
      ffn1, FF, WT2, b2, outf, M, H, FF, 0, 1);
  ln2_kernel<<<dim3(M), tb, 0, stream>>>(outf, hb, ln2g, ln2b, outf);
}